// Round 5
// baseline (511.301 us; speedup 1.0000x reference)
//
#include <hip/hip_runtime.h>
#include <hip/hip_bf16.h>

typedef __hip_bfloat16 bf16;
typedef unsigned short us;
typedef unsigned int u32;
typedef __attribute__((ext_vector_type(8))) short short8;
typedef __attribute__((ext_vector_type(8))) unsigned short ushortx8;
typedef __attribute__((ext_vector_type(4))) float f32x4;

#define HW 65536
#define IMW 256
#define IMH 256

static __device__ __forceinline__ float u2f(us u) {
  return __uint_as_float(((unsigned)u) << 16);
}
static __device__ __forceinline__ us f2bu(float x) {
  bf16 h = __float2bfloat16(x);
  return *reinterpret_cast<us*>(&h);
}
static __device__ __forceinline__ unsigned pk2(float a, float b) {
  return (unsigned)f2bu(a) | ((unsigned)f2bu(b) << 16);
}

// async global->LDS 16B: per-lane global src, wave-uniform LDS dest
static __device__ __forceinline__ void gload_lds16(const void* g, void* l) {
  __builtin_amdgcn_global_load_lds(
      (const __attribute__((address_space(1))) u32*)g,
      (__attribute__((address_space(3))) u32*)l, 16, 0, 0);
}

// ---------------------------------------------------------------------------
// Weight prep: fp32 [oc][ci][3][3] -> bf16 chunk layout [t][kc][g][m][q][8].
// One (t,kc) chunk = G*64 16B-slots, consumed as one LDS stage in the conv.
// oc = g*16+m ; k = kc*32 + q*8 + e (zero-padded K).
// ---------------------------------------------------------------------------
struct PrepArgs {
  const float* src[9];
  us* dst[9];
  int OC[9], CIN[9], KPAD[9];
};

__global__ __launch_bounds__(256) void prep_weights(PrepArgs a) {
  int j = blockIdx.y;
  int n = blockIdx.x * 256 + threadIdx.x;
  int OC = a.OC[j], CIN = a.CIN[j], KPAD = a.KPAD[j];
  int tot = 9 * OC * KPAD;
  if (n >= tot) return;
  int G = OC >> 4, NKC = KPAD >> 5;
  int e = n & 7;
  int q = (n >> 3) & 3;
  int m = (n >> 5) & 15;
  int rest = n >> 9;            // (t*NKC + kc)*G + g
  int g = rest % G;
  int tkc = rest / G;
  int kc = tkc % NKC;
  int t = tkc / NKC;
  int oc = g * 16 + m;
  int k = kc * 32 + q * 8 + e;
  float v = (k < CIN) ? a.src[j][(size_t)(oc * CIN + k) * 9 + t] : 0.f;
  a.dst[j][n] = f2bu(v);
}

// ---------------------------------------------------------------------------
// frame fp32 NCHW [b][96][HW] -> NHWC bf16 [b][HW][96]
// ---------------------------------------------------------------------------
__global__ __launch_bounds__(256) void frame_to_nhwc(const float* __restrict__ frame,
                                                     unsigned* __restrict__ fn) {
  int pix = blockIdx.x * 256 + threadIdx.x;
  int b = blockIdx.y;
  const float* s = frame + (size_t)b * 96 * HW + pix;
  unsigned u[48];
#pragma unroll
  for (int j = 0; j < 48; ++j)
    u[j] = pk2(s[(size_t)(2 * j) * HW], s[(size_t)(2 * j + 1) * HW]);
  unsigned* d = fn + ((size_t)b * HW + pix) * 48;
#pragma unroll
  for (int j = 0; j < 12; ++j) {
    uint4 w;
    w.x = u[4 * j]; w.y = u[4 * j + 1]; w.z = u[4 * j + 2]; w.w = u[4 * j + 3];
    *(uint4*)&d[4 * j] = w;
  }
}

// ---------------------------------------------------------------------------
// qk_in build from NHWC frame: warp01 | frame[:,1] | warp21 | flows
// -> qk NHWC bf16 [b][HW][100]
// ---------------------------------------------------------------------------
static __device__ void warp_nhwc(const us* __restrict__ fn, size_t bbase, int coff,
                                 float x, float y, unsigned* uo) {
  float x0f = floorf(x), y0f = floorf(y);
  float lx = x - x0f, ly = y - y0f;
  int x0 = (int)x0f, y0 = (int)y0f;
  float wt[4] = {(1.f - lx) * (1.f - ly), lx * (1.f - ly), (1.f - lx) * ly, lx * ly};
  float acc[32] = {};
#pragma unroll
  for (int k = 0; k < 4; ++k) {
    int xi = x0 + (k & 1), yi = y0 + (k >> 1);
    if ((unsigned)xi < IMW && (unsigned)yi < IMH) {
      const ushortx8* s =
          (const ushortx8*)(fn + (bbase + (size_t)yi * IMW + xi) * 96 + coff);
      float w = wt[k];
#pragma unroll
      for (int cj = 0; cj < 4; ++cj) {
        ushortx8 vv = s[cj];
#pragma unroll
        for (int e = 0; e < 8; ++e)
          acc[cj * 8 + e] = fmaf(w, u2f(vv[e]), acc[cj * 8 + e]);
      }
    }
  }
#pragma unroll
  for (int j = 0; j < 16; ++j) uo[j] = pk2(acc[2 * j], acc[2 * j + 1]);
}

__global__ __launch_bounds__(256) void build_qkin(
    const us* __restrict__ fn, const float* __restrict__ flowf,
    const float* __restrict__ flowb, unsigned* __restrict__ qk) {
  int pix = blockIdx.x * 256 + threadIdx.x;
  int b = blockIdx.y;
  int px = pix & 255, py = pix >> 8;

  float fbx = flowb[((size_t)(b * 2 + 0) * 2 + 0) * HW + pix];
  float fby = flowb[((size_t)(b * 2 + 0) * 2 + 1) * HW + pix];
  float ffx = flowf[((size_t)(b * 2 + 1) * 2 + 0) * HW + pix];
  float ffy = flowf[((size_t)(b * 2 + 1) * 2 + 1) * HW + pix];

  unsigned u[50];
  {
    const unsigned* s = (const unsigned*)(fn + ((size_t)b * HW + pix) * 96);
#pragma unroll
    for (int j = 0; j < 16; ++j) u[16 + j] = s[16 + j];
  }
  u[48] = pk2(ffx, ffy);
  u[49] = pk2(fbx, fby);

  warp_nhwc(fn, (size_t)b * HW, 0, (float)px + fbx, (float)py + fby, &u[0]);
  warp_nhwc(fn, (size_t)b * HW, 64, (float)px + ffx, (float)py + ffy, &u[32]);

  unsigned* qb = qk + ((size_t)b * HW + pix) * 50;
#pragma unroll
  for (int j = 0; j < 25; ++j) {
    uint2 t;
    t.x = u[2 * j];
    t.y = u[2 * j + 1];
    *(uint2*)(qb + 2 * j) = t;
  }
}

// ---------------------------------------------------------------------------
// MFMA implicit-GEMM 3x3 conv, NHWC bf16 input.
// r5: act whole-K in LDS (one stage); weights streamed through a small
// double-buffered LDS chunk (one (tap,kc) chunk = G KB) staged with
// global_load_lds (linear memcpy thanks to the [t][kc][g][m][q][8] layout).
// Each weight byte enters the CU once per block (was 2x per block via
// per-wave register loads -> L2-BW-bound at ~17% MfmaUtil).
// One barrier per chunk; MFMAs of chunk u cover the L2 latency of chunk u+1.
// Block 256 thr = 4 waves = (2 g-halves) x (2 row-halves); tile 16x8 px.
// ---------------------------------------------------------------------------
template <int CIN, int CST, int KPAD, int DIL, int G, int ZDIV, int CSUB,
          int RES, int OUTMODE, bool LRELU>
__global__ __launch_bounds__(256) void conv3x3_mfma(
    const us* __restrict__ in, const us* __restrict__ W2,
    const float* __restrict__ bias, void* __restrict__ out, int out_cst,
    int out_coff, float* __restrict__ outB, const float* __restrict__ res,
    int res_cst, int res_coff) {
  constexpr int OC = G * 16;
  constexpr int COLS = 16 + 2 * DIL;
  constexpr int ROWS = 8 + 2 * DIL;
  constexpr int HALO = ROWS * COLS;
  constexpr int CIPAD = KPAD + 8;
  constexpr int CH = KPAD / 8;
  constexpr int NKC = KPAD / 32;
  constexpr int GW0 = (G + 1) / 2;
  constexpr int NU = 9 * NKC;
  constexpr int WSLOT = G * 64;           // 16B slots per weight chunk
  __shared__ alignas(16) short lds[HALO * CIPAD];
  __shared__ alignas(16) short wlds[2][WSLOT * 8];

  const int z = blockIdx.z;
  const int bin = z / ZDIV;
  const int coff = (z % ZDIV) * CSUB;
  const int px0 = blockIdx.x * 16, py0 = blockIdx.y * 8;
  const int lane = threadIdx.x & 63;
  const int wv = threadIdx.x >> 6;
  const int m = lane & 15, q = lane >> 4;
  const int gh = wv & 1, rh = wv >> 1;
  const int goff = gh * GW0;

  f32x4 acc[GW0][4];
#pragma unroll
  for (int g = 0; g < GW0; ++g)
#pragma unroll
    for (int r = 0; r < 4; ++r) acc[g][r] = 0.f;

  // ---- stage whole-K NHWC halo tile into LDS [pos][ci], coalesced ----
  for (int c = threadIdx.x; c < HALO * CH; c += 256) {
    int p = c / CH, cb = c - p * CH;
    int row = p / COLS, col = p - row * COLS;
    int gy = py0 + row - DIL, gx = px0 + col - DIL;
    bool ok = ((unsigned)gy < IMH) && ((unsigned)gx < IMW);
    int ci0 = cb * 8;
    const us* gp = in + ((size_t)bin * HW + (size_t)gy * IMW + gx) * CST + coff + ci0;
    if (CIN == KPAD) {
      short8 v = (short8)0;
      if (ok) v = *(const short8*)gp;
      *(short8*)&lds[p * CIPAD + ci0] = v;
    } else {
      uint2 h0; h0.x = 0; h0.y = 0;
      uint2 h1; h1.x = 0; h1.y = 0;
      if (ok && ci0 + 4 <= CIN) h0 = *(const uint2*)gp;
      if (ok && ci0 + 8 <= CIN) h1 = *(const uint2*)(gp + 4);
      *(uint2*)&lds[p * CIPAD + ci0] = h0;
      *(uint2*)&lds[p * CIPAD + ci0 + 4] = h1;
    }
  }

  // ---- stage weight chunk 0 (async, drained by the barrier) ----------
#pragma unroll
  for (int r = 0; r < (G + 3) / 4; ++r) {
    int blk = r * 4 + wv;                 // 64-slot block index
    if (blk * 64 < WSLOT)
      gload_lds16(W2 + (size_t)(blk * 64 + lane) * 8, &wlds[0][blk * 64 * 8]);
  }
  __syncthreads();

  // ---- main loop over (tap, kc) chunks -------------------------------
  int buf = 0;
#pragma unroll 1
  for (int u = 0; u < NU; ++u) {
    // stage next chunk into the other buffer (async)
    if (u + 1 < NU) {
      const us* wn = W2 + (size_t)(u + 1) * (WSLOT * 8);
#pragma unroll
      for (int r = 0; r < (G + 3) / 4; ++r) {
        int blk = r * 4 + wv;
        if (blk * 64 < WSLOT)
          gload_lds16(wn + (size_t)(blk * 64 + lane) * 8,
                      &wlds[buf ^ 1][blk * 64 * 8]);
      }
    }

    const int t = u / NKC, kc = u - t * NKC;
    const int dy = t / 3 - 1, dx = t - (t / 3) * 3 - 1;

    short8 bfr[4];
#pragma unroll
    for (int r = 0; r < 4; ++r) {
      int rr = rh * 4 + r + DIL + dy * DIL;
      int cc = m + DIL + dx * DIL;
      bfr[r] = *(const short8*)&lds[(rr * COLS + cc) * CIPAD + kc * 32 + q * 8];
    }
    short8 af[GW0];
#pragma unroll
    for (int g = 0; g < GW0; ++g)
      if (goff + g < G)
        af[g] = *(const short8*)&wlds[buf][(((goff + g) * 16 + m) * 4 + q) * 8];

#pragma unroll
    for (int g = 0; g < GW0; ++g)
      if (goff + g < G)
#pragma unroll
        for (int r = 0; r < 4; ++r)
          acc[g][r] = __builtin_amdgcn_mfma_f32_16x16x32_bf16(af[g], bfr[r],
                                                              acc[g][r], 0, 0, 0);
    __syncthreads();
    buf ^= 1;
  }

  // ---- epilogue -------------------------------------------------------
#pragma unroll
  for (int g = 0; g < GW0; ++g) {
    if (goff + g < G) {
      int oc0 = (goff + g) * 16 + q * 4;
      f32x4 bb = *(const f32x4*)&bias[oc0];
#pragma unroll
      for (int r = 0; r < 4; ++r) {
        int py = py0 + rh * 4 + r;
        int px = px0 + m;
        size_t pix = (size_t)py * IMW + px;
        f32x4 v;
#pragma unroll
        for (int e = 0; e < 4; ++e) {
          float x = acc[g][r][e] + bb[e];
          if (LRELU) x = x >= 0.f ? x : 0.1f * x;
          v[e] = x;
        }
        if (RES == 1) {
          f32x4 rv = *(const f32x4*)&res[((size_t)z * HW + pix) * res_cst + oc0];
#pragma unroll
          for (int e = 0; e < 4; ++e) v[e] += rv[e];
        }
        if (RES == 2) {
#pragma unroll
          for (int e = 0; e < 4; ++e)
            v[e] += res[((size_t)z * res_cst + res_coff + oc0 + e) * HW + pix];
        }
        if (OUTMODE == 0 || OUTMODE == 3) {
          uint2 w;
          w.x = pk2(v[0], v[1]);
          w.y = pk2(v[2], v[3]);
          *(uint2*)&((us*)out)[((size_t)z * HW + pix) * out_cst + out_coff + oc0] = w;
        }
        if (OUTMODE == 2)
          *(f32x4*)&((float*)out)[((size_t)z * HW + pix) * out_cst + oc0] = v;
        if (OUTMODE == 3)
          *(f32x4*)&outB[((size_t)z * HW + pix) * 32 + oc0] = v;
      }
    }
  }
}

// ---------------------------------------------------------------------------
// Deformable attention. valp [6][HW][32] bf16; off [2][HW][96] bf16;
// aw [2][HW][48] f32; out attn [2][HW][32] bf16.
// Parallelized over (pixel, head): tid&3 = head, tid>>2 = pixel-in-block.
// ---------------------------------------------------------------------------
__global__ __launch_bounds__(256) void deform_attn(
    const us* __restrict__ valp, const us* __restrict__ off,
    const float* __restrict__ aw, us* __restrict__ outp) {
  int tid = threadIdx.x;
  int hh = tid & 3;
  int pix = blockIdx.x * 64 + (tid >> 2);
  int b = blockIdx.y;
  int px = pix & (IMW - 1), py = pix >> 8;
  float refx = ((float)px + 0.5f) * (1.0f / IMW);
  float refy = ((float)py + 0.5f) * (1.0f / IMH);

  ushortx8 o8[3];
  {
    const ushortx8* ob =
        (const ushortx8*)(off + ((size_t)b * HW + pix) * 96 + hh * 24);
#pragma unroll
    for (int j = 0; j < 3; ++j) o8[j] = ob[j];
  }
  f32x4 a4[3];
  {
    const f32x4* ab = (const f32x4*)(aw + ((size_t)b * HW + pix) * 48 + hh * 12);
#pragma unroll
    for (int j = 0; j < 3; ++j) a4[j] = ab[j];
  }

  float wv[12];
  float mx = -1e30f;
#pragma unroll
  for (int lp = 0; lp < 12; ++lp) {
    wv[lp] = a4[lp >> 2][lp & 3];
    mx = fmaxf(mx, wv[lp]);
  }
  float s = 0.f;
#pragma unroll
  for (int lp = 0; lp < 12; ++lp) {
    wv[lp] = __expf(wv[lp] - mx);
    s += wv[lp];
  }
  float inv = 1.f / s;

  float acc[8] = {0.f, 0.f, 0.f, 0.f, 0.f, 0.f, 0.f, 0.f};
#pragma unroll 1
  for (int l = 0; l < 3; ++l) {
    const us* vbase = valp + ((size_t)(b * 3 + l) * HW) * 32 + hh * 8;
#pragma unroll
    for (int p = 0; p < 4; ++p) {
      int ch = l * 8 + p * 2;
      float ox = u2f(o8[ch >> 3][ch & 7]);
      float oy = u2f(o8[(ch + 1) >> 3][(ch + 1) & 7]);
      float x = (refx + ox * (1.0f / IMW)) * (float)IMW - 0.5f;
      float y = (refy + oy * (1.0f / IMH)) * (float)IMH - 0.5f;
      float x0f = floorf(x), y0f = floorf(y);
      float lx = x - x0f, ly = y - y0f;
      int x0 = (int)x0f, y0 = (int)y0f;
      float a = wv[l * 4 + p] * inv;
      float cw[4] = {(1.f - lx) * (1.f - ly) * a, lx * (1.f - ly) * a,
                     (1.f - lx) * ly * a, lx * ly * a};
#pragma unroll
      for (int k = 0; k < 4; ++k) {
        int xi = x0 + (k & 1), yi = y0 + (k >> 1);
        if ((unsigned)xi < IMW && (unsigned)yi < IMH) {
          const ushortx8 u = *(const ushortx8*)(vbase + (size_t)(yi * IMW + xi) * 32);
          float wgt = cw[k];
#pragma unroll
          for (int dd = 0; dd < 8; ++dd) acc[dd] = fmaf(wgt, u2f(u[dd]), acc[dd]);
        }
      }
    }
  }
  ushortx8 sv;
#pragma unroll
  for (int dd = 0; dd < 8; ++dd) sv[dd] = f2bu(acc[dd]);
  *(ushortx8*)(outp + ((size_t)b * HW + pix) * 32 + hh * 8) = sv;
}

// ---------------------------------------------------------------------------
// srcframe[:,1] fp32 NCHW -> out1b NHWC-64 ch32..63 (bf16)
// ---------------------------------------------------------------------------
__global__ __launch_bounds__(256) void copy_src(const float* __restrict__ src,
                                                unsigned* __restrict__ out1b) {
  int pix = blockIdx.x * 256 + threadIdx.x;
  int b = blockIdx.y;
  const float* s = src + ((size_t)(b * 3 + 1) * 32) * HW + pix;
  unsigned u[16];
#pragma unroll
  for (int j = 0; j < 16; ++j)
    u[j] = pk2(s[(size_t)(2 * j) * HW], s[(size_t)(2 * j + 1) * HW]);
  unsigned* d = out1b + ((size_t)b * HW + pix) * 32 + 16;
#pragma unroll
  for (int j = 0; j < 4; ++j) {
    uint4 w;
    w.x = u[4 * j]; w.y = u[4 * j + 1]; w.z = u[4 * j + 2]; w.w = u[4 * j + 3];
    *(uint4*)&d[4 * j] = w;
  }
}

// ---------------------------------------------------------------------------
// final 1x1 conv + lrelu: out2 NHWC-32 f32 -> d_out fp32 NCHW
// ---------------------------------------------------------------------------
__global__ __launch_bounds__(256) void conv1x1_fu(
    const float* __restrict__ in, const float* __restrict__ wgt,
    const float* __restrict__ bias, float* __restrict__ out) {
  int pix = blockIdx.x * 256 + threadIdx.x;
  int b = blockIdx.y;
  float vin[32];
  {
    const f32x4* s = (const f32x4*)(in + ((size_t)b * HW + pix) * 32);
#pragma unroll
    for (int j = 0; j < 8; ++j) {
      f32x4 v = s[j];
#pragma unroll
      for (int e = 0; e < 4; ++e) vin[4 * j + e] = v[e];
    }
  }
#pragma unroll 1
  for (int oc = 0; oc < 32; ++oc) {
    float a = bias[oc];
#pragma unroll
    for (int ci = 0; ci < 32; ++ci) a = fmaf(wgt[oc * 32 + ci], vin[ci], a);
    a = a >= 0.f ? a : 0.1f * a;
    out[((size_t)b * 32 + oc) * HW + pix] = a;
  }
}

// ---------------------------------------------------------------------------
extern "C" void kernel_launch(void* const* d_in, const int* in_sizes, int n_in,
                              void* d_out, int out_size, void* d_ws, size_t ws_size,
                              hipStream_t stream) {
  (void)in_sizes; (void)n_in; (void)out_size;
  // Footprint: 25,614,592 floats = 102.46 MB (same as prior rounds, known OK).
  if (ws_size < 25614592ull * 4) return;

  const float* frame = (const float*)d_in[0];
  const float* srcframe = (const float*)d_in[1];
  const float* flowf = (const float*)d_in[2];
  const float* flowb = (const float*)d_in[3];

  float* ws = (float*)d_ws;
  us* wsu = (us*)d_ws;

  // bf16 weights (chunk layout), offsets in shorts (end 373,248 = 186,624 fl)
  static const int w2off[9] = {0,      110592, 193536, 202752, 285696,
                               327168, 336384, 345600, 364032};
  // Activation slots (float offsets):
  //  S1 @   186,624 (6,291,456): fnhwc -> offb -> ff1out
  //  S2 @ 6,478,080 (6,553,600): qk -> V -> awb(f32) -> out1b
  //  S3 @13,031,680 (6,291,456): Q -> attn + convout -> out2(f32)
  //  S4 @19,323,136 (6,291,456): Vp -> out1f(f32)
  us* fnhwc = (us*)(ws + 186624);
  unsigned* qk_u = (unsigned*)(ws + 6478080);
  us* qk = (us*)qk_u;
  us* Q = (us*)(ws + 13031680);
  us* V = (us*)(ws + 6478080);
  us* Vp = (us*)(ws + 19323136);
  us* offb = (us*)(ws + 186624);
  float* awb = (float*)(ws + 6478080);
  us* attn = (us*)(ws + 13031680);
  us* convout = (us*)(ws + 13031680 + 2097152);
  us* out1b = (us*)(ws + 6478080);
  unsigned* out1b_u = (unsigned*)out1b;
  float* out1f = (float*)(ws + 19323136);
  us* ff1out = (us*)(ws + 186624);
  float* out2 = (float*)(ws + 13031680);

  // 1) weight prep
  {
    PrepArgs pa;
    static const int srcidx[9] = {4, 6, 8, 10, 12, 14, 16, 18, 20};
    static const int OCs[9] = {96, 96, 32, 96, 48, 32, 32, 32, 32};
    static const int CINs[9] = {100, 96, 32, 96, 96, 32, 32, 64, 32};
    static const int KPADs[9] = {128, 96, 32, 96, 96, 32, 32, 64, 32};
    for (int i = 0; i < 9; ++i) {
      pa.src[i] = (const float*)d_in[srcidx[i]];
      pa.dst[i] = wsu + w2off[i];
      pa.OC[i] = OCs[i];
      pa.CIN[i] = CINs[i];
      pa.KPAD[i] = KPADs[i];
    }
    prep_weights<<<dim3(432, 9), 256, 0, stream>>>(pa);
  }

  // 2) frame -> NHWC bf16
  frame_to_nhwc<<<dim3(256, 2), 256, 0, stream>>>(frame, (unsigned*)fnhwc);

  // 3) qk_in NHWC-100
  build_qkin<<<dim3(256, 2), 256, 0, stream>>>(fnhwc, flowf, flowb, qk_u);

  dim3 cg2(16, 32, 2);

  // 4) qureys = lrelu(conv_qk)  100->96  (KPAD=128, G=6)
  conv3x3_mfma<100, 100, 128, 1, 6, 1, 0, 0, 0, true><<<cg2, 256, 0, stream>>>(
      qk, wsu + w2off[0], (const float*)d_in[5], Q, 96, 0, nullptr, nullptr, 0, 0);

  // 5) value = conv_v(fnhwc) 96->96
  conv3x3_mfma<96, 96, 96, 1, 6, 1, 0, 0, 0, false><<<cg2, 256, 0, stream>>>(
      fnhwc, wsu + w2off[1], (const float*)d_in[7], V, 96, 0, nullptr, nullptr, 0, 0);

  // 6) val = conv_vp per (b,l) 32->32 -> Vp [6][HW][32]
  conv3x3_mfma<32, 96, 32, 1, 2, 3, 32, 0, 0, false><<<dim3(16, 32, 6), 256, 0, stream>>>(
      V, wsu + w2off[2], (const float*)d_in[9], Vp, 32, 0, nullptr, nullptr, 0, 0);

  // 7) off = conv_off(Q) 96->96 (S1; fnhwc dead)
  conv3x3_mfma<96, 96, 96, 1, 6, 1, 0, 0, 0, false><<<cg2, 256, 0, stream>>>(
      Q, wsu + w2off[3], (const float*)d_in[11], offb, 96, 0, nullptr, nullptr, 0, 0);

  // 8) aw = conv_aw(Q) 96->48 f32 NHWC (S2; V dead)  G=3
  conv3x3_mfma<96, 96, 96, 1, 3, 1, 0, 0, 2, false><<<cg2, 256, 0, stream>>>(
      Q, wsu + w2off[4], (const float*)d_in[13], awb, 48, 0, nullptr, nullptr, 0, 0);

  // 9) deformable attention -> attn (S3; Q dead)  [(pixel,head)-parallel]
  deform_attn<<<dim3(1024, 2), 256, 0, stream>>>(Vp, offb, awb, attn);

  // 10) conv_out(attn) 32->32 (S3 tail)
  conv3x3_mfma<32, 32, 32, 1, 2, 1, 0, 0, 0, false><<<cg2, 256, 0, stream>>>(
      attn, wsu + w2off[5], (const float*)d_in[15], convout, 32, 0, nullptr, nullptr, 0, 0);

  // 11) out1 = conv_ffd(convout) + frame[:,1] -> out1b(NHWC-64 bf16) + out1f(f32)
  conv3x3_mfma<32, 32, 32, 1, 2, 1, 0, 2, 3, false><<<cg2, 256, 0, stream>>>(
      convout, wsu + w2off[6], (const float*)d_in[17], out1b, 64, 0, out1f, frame, 96, 32);

  // 12) srcframe[:,1] -> out1b ch32..63
  copy_src<<<dim3(256, 2), 256, 0, stream>>>(srcframe, out1b_u);

  // 13) ff1 = lrelu(conv dil=2 on out1b 64ch) -> ff1out (S1; offb dead)
  conv3x3_mfma<64, 64, 64, 2, 2, 1, 0, 0, 0, true><<<cg2, 256, 0, stream>>>(
      out1b, wsu + w2off[7], (const float*)d_in[19], ff1out, 32, 0, nullptr, nullptr, 0, 0);

  // 14) out2 = conv_ff2(ff1out) + out1f -> f32 NHWC-32 (S3; attn/convout dead)
  conv3x3_mfma<32, 32, 32, 1, 2, 1, 0, 1, 2, false><<<cg2, 256, 0, stream>>>(
      ff1out, wsu + w2off[8], (const float*)d_in[21], out2, 32, 0, nullptr, out1f, 32, 0);

  // 15) out = lrelu(conv_fu 1x1(out2)) -> fp32 NCHW d_out
  conv1x1_fu<<<dim3(256, 2), 256, 0, stream>>>(out2, (const float*)d_in[22],
                                               (const float*)d_in[23], (float*)d_out);
}

// Round 6
// 465.022 us; speedup vs baseline: 1.0995x; 1.0995x over previous
//
#include <hip/hip_runtime.h>
#include <hip/hip_bf16.h>

typedef __hip_bfloat16 bf16;
typedef unsigned short us;
typedef unsigned int u32;
typedef __attribute__((ext_vector_type(8))) short short8;
typedef __attribute__((ext_vector_type(8))) unsigned short ushortx8;
typedef __attribute__((ext_vector_type(4))) float f32x4;
typedef __attribute__((ext_vector_type(16))) float f32x16;

#define HW 65536
#define IMW 256
#define IMH 256

static __device__ __forceinline__ float u2f(us u) {
  return __uint_as_float(((unsigned)u) << 16);
}
static __device__ __forceinline__ us f2bu(float x) {
  bf16 h = __float2bfloat16(x);
  return *reinterpret_cast<us*>(&h);
}
static __device__ __forceinline__ unsigned pk2(float a, float b) {
  return (unsigned)f2bu(a) | ((unsigned)f2bu(b) << 16);
}

// async global->LDS 16B: per-lane global src, wave-uniform LDS dest
static __device__ __forceinline__ void gload_lds16(const void* g, void* l) {
  __builtin_amdgcn_global_load_lds(
      (const __attribute__((address_space(1))) u32*)g,
      (__attribute__((address_space(3))) u32*)l, 16, 0, 0);
}

// ---------------------------------------------------------------------------
// Weight prep. Two layouts:
// LAY=0 (burst, for 16x16 template): [t][g][kc][q][m][8]; oc=g*16+m, k=kc*32+q*8+e
// LAY=1 (m32 chunks, for 32x32 template): [t][kh][j][lane][8];
//        oc=j*32+(lane&31), k=kh*16+(lane>>5)*8+e
// Both zero-pad K to KPAD.
// ---------------------------------------------------------------------------
struct PrepArgs {
  const float* src[9];
  us* dst[9];
  int OC[9], CIN[9], KPAD[9], LAY[9];
};

__global__ __launch_bounds__(256) void prep_weights(PrepArgs a) {
  int j = blockIdx.y;
  int n = blockIdx.x * 256 + threadIdx.x;
  int OC = a.OC[j], CIN = a.CIN[j], KPAD = a.KPAD[j];
  int tot = 9 * OC * KPAD;
  if (n >= tot) return;
  int oc, k;
  if (a.LAY[j] == 0) {
    int G = OC >> 4, NKC = KPAD >> 5;
    int e = n & 7;
    int m = (n >> 3) & 15;
    int q = (n >> 7) & 3;
    int rest = n >> 9;          // (t*G + g)*NKC + kc
    int kc = rest % NKC;
    int tg = rest / NKC;
    int g = tg % G;
    int t = tg / G;
    oc = g * 16 + m;
    k = kc * 32 + q * 8 + e;
    float v = (k < CIN) ? a.src[j][(size_t)(oc * CIN + k) * 9 + t] : 0.f;
    a.dst[j][n] = f2bu(v);
  } else {
    int OCT = OC >> 5, KH = KPAD >> 4;
    int e = n & 7;
    int l = (n >> 3) & 63;
    int rest = n >> 9;          // ((t*KH + kh)*OCT + jt)
    int jt = rest % OCT;
    int u = rest / OCT;
    int kh = u % KH;
    int t = u / KH;
    oc = jt * 32 + (l & 31);
    k = kh * 16 + (l >> 5) * 8 + e;
    float v = (k < CIN) ? a.src[j][(size_t)(oc * CIN + k) * 9 + t] : 0.f;
    a.dst[j][n] = f2bu(v);
  }
}

// ---------------------------------------------------------------------------
// frame fp32 NCHW [b][96][HW] -> NHWC bf16 [b][HW][96]
// ---------------------------------------------------------------------------
__global__ __launch_bounds__(256) void frame_to_nhwc(const float* __restrict__ frame,
                                                     unsigned* __restrict__ fn) {
  int pix = blockIdx.x * 256 + threadIdx.x;
  int b = blockIdx.y;
  const float* s = frame + (size_t)b * 96 * HW + pix;
  unsigned u[48];
#pragma unroll
  for (int j = 0; j < 48; ++j)
    u[j] = pk2(s[(size_t)(2 * j) * HW], s[(size_t)(2 * j + 1) * HW]);
  unsigned* d = fn + ((size_t)b * HW + pix) * 48;
#pragma unroll
  for (int j = 0; j < 12; ++j) {
    uint4 w;
    w.x = u[4 * j]; w.y = u[4 * j + 1]; w.z = u[4 * j + 2]; w.w = u[4 * j + 3];
    *(uint4*)&d[4 * j] = w;
  }
}

// ---------------------------------------------------------------------------
// qk_in build from NHWC frame: warp01 | frame[:,1] | warp21 | flows
// -> qk NHWC bf16 [b][HW][100]
// ---------------------------------------------------------------------------
static __device__ void warp_nhwc(const us* __restrict__ fn, size_t bbase, int coff,
                                 float x, float y, unsigned* uo) {
  float x0f = floorf(x), y0f = floorf(y);
  float lx = x - x0f, ly = y - y0f;
  int x0 = (int)x0f, y0 = (int)y0f;
  float wt[4] = {(1.f - lx) * (1.f - ly), lx * (1.f - ly), (1.f - lx) * ly, lx * ly};
  float acc[32] = {};
#pragma unroll
  for (int k = 0; k < 4; ++k) {
    int xi = x0 + (k & 1), yi = y0 + (k >> 1);
    if ((unsigned)xi < IMW && (unsigned)yi < IMH) {
      const ushortx8* s =
          (const ushortx8*)(fn + (bbase + (size_t)yi * IMW + xi) * 96 + coff);
      float w = wt[k];
#pragma unroll
      for (int cj = 0; cj < 4; ++cj) {
        ushortx8 vv = s[cj];
#pragma unroll
        for (int e = 0; e < 8; ++e)
          acc[cj * 8 + e] = fmaf(w, u2f(vv[e]), acc[cj * 8 + e]);
      }
    }
  }
#pragma unroll
  for (int j = 0; j < 16; ++j) uo[j] = pk2(acc[2 * j], acc[2 * j + 1]);
}

__global__ __launch_bounds__(256) void build_qkin(
    const us* __restrict__ fn, const float* __restrict__ flowf,
    const float* __restrict__ flowb, unsigned* __restrict__ qk) {
  int pix = blockIdx.x * 256 + threadIdx.x;
  int b = blockIdx.y;
  int px = pix & 255, py = pix >> 8;

  float fbx = flowb[((size_t)(b * 2 + 0) * 2 + 0) * HW + pix];
  float fby = flowb[((size_t)(b * 2 + 0) * 2 + 1) * HW + pix];
  float ffx = flowf[((size_t)(b * 2 + 1) * 2 + 0) * HW + pix];
  float ffy = flowf[((size_t)(b * 2 + 1) * 2 + 1) * HW + pix];

  unsigned u[50];
  {
    const unsigned* s = (const unsigned*)(fn + ((size_t)b * HW + pix) * 96);
#pragma unroll
    for (int j = 0; j < 16; ++j) u[16 + j] = s[16 + j];
  }
  u[48] = pk2(ffx, ffy);
  u[49] = pk2(fbx, fby);

  warp_nhwc(fn, (size_t)b * HW, 0, (float)px + fbx, (float)py + fby, &u[0]);
  warp_nhwc(fn, (size_t)b * HW, 64, (float)px + ffx, (float)py + ffy, &u[32]);

  unsigned* qb = qk + ((size_t)b * HW + pix) * 50;
#pragma unroll
  for (int j = 0; j < 25; ++j) {
    uint2 t;
    t.x = u[2 * j];
    t.y = u[2 * j + 1];
    *(uint2*)(qb + 2 * j) = t;
  }
}

// ---------------------------------------------------------------------------
// r6 NEW: 32x32x16-MFMA implicit-GEMM 3x3 conv for OC multiple of 32.
// Tile 16x8 px; 4 waves, wave w owns a 32-px strip (rows 2w..2w+1 x 16 cols).
// B-frag: lane n=lane&31 -> (subrow n>>4, col n&15); k=(lane>>5)*8+e.
// A-frag: oc=j*32+(lane&31), k=(lane>>5)*8+e  (extrapolated from the
// verified 16x16x32 mapping row=lane&15,k=(lane>>4)*8+e).
// C/D (HW-verified): col=lane&31, row=(reg&3)+8*(reg>>2)+4*(lane>>5).
// Weights stream via double-buffered LDS chunks (gload_lds, linear reads).
// Per k16-step: 1 B-read + OCT A-reads + OCT MFMAs (24cyc MFMA / 48cyc LDS
// at OCT=3 vs 58/84 in the 16x16 template).
// ---------------------------------------------------------------------------
template <int CIN, int CST, int KPAD, int OCT, int KHC, bool LRELU>
__global__ __launch_bounds__(256) void conv3x3_m32(
    const us* __restrict__ in, const us* __restrict__ W2,
    const float* __restrict__ bias, us* __restrict__ out, int out_cst,
    int out_coff) {
  constexpr int COLS = 18, ROWS = 10, HALO = COLS * ROWS;
  constexpr int CIPAD = KPAD + 8;
  constexpr int CH = KPAD / 8;
  constexpr int KH = KPAD / 16;
  constexpr int SPT = KH / KHC;          // stages per tap
  constexpr int NSTG = 9 * SPT;
  constexpr int CHB = KHC * OCT;         // 1KB blocks per weight chunk
  __shared__ alignas(16) short lds[HALO * CIPAD];
  __shared__ alignas(16) short wlds[2][CHB * 512];

  const int z = blockIdx.z;
  const int px0 = blockIdx.x * 16, py0 = blockIdx.y * 8;
  const int lane = threadIdx.x & 63;
  const int wv = threadIdx.x >> 6;
  const int n = lane & 31;
  const int sr = n >> 4;
  const int colp = n & 15;
  const int kq = lane >> 5;

  f32x16 acc[OCT];
#pragma unroll
  for (int j = 0; j < OCT; ++j) acc[j] = 0.f;

  // ---- stage whole-K NHWC halo tile into LDS [pos][ci], coalesced ----
  for (int c = threadIdx.x; c < HALO * CH; c += 256) {
    int p = c / CH, cb = c - p * CH;
    int row = p / COLS, col = p - row * COLS;
    int gy = py0 + row - 1, gx = px0 + col - 1;
    bool ok = ((unsigned)gy < IMH) && ((unsigned)gx < IMW);
    int ci0 = cb * 8;
    const us* gp = in + ((size_t)z * HW + (size_t)gy * IMW + gx) * CST + ci0;
    if (CIN == KPAD) {
      short8 v = (short8)0;
      if (ok) v = *(const short8*)gp;
      *(short8*)&lds[p * CIPAD + ci0] = v;
    } else {
      uint2 h0; h0.x = 0; h0.y = 0;
      uint2 h1; h1.x = 0; h1.y = 0;
      if (ok && ci0 + 4 <= CIN) h0 = *(const uint2*)gp;
      if (ok && ci0 + 8 <= CIN) h1 = *(const uint2*)(gp + 4);
      *(uint2*)&lds[p * CIPAD + ci0] = h0;
      *(uint2*)&lds[p * CIPAD + ci0 + 4] = h1;
    }
  }

  // ---- stage weight chunk 0 (async, drained by the barrier) ----------
#pragma unroll
  for (int r = 0; r < (CHB + 3) / 4; ++r) {
    int blk = r * 4 + wv;
    if (blk < CHB)
      gload_lds16(W2 + (size_t)(blk * 64 + lane) * 8, &wlds[0][blk * 512]);
  }
  __syncthreads();

  const int lanebase = ((wv * 2 + sr) * COLS + colp) * CIPAD + kq * 8;

  int buf = 0;
#pragma unroll 1
  for (int s = 0; s < NSTG; ++s) {
    if (s + 1 < NSTG) {
      const us* wn = W2 + (size_t)(s + 1) * (CHB * 512);
#pragma unroll
      for (int r = 0; r < (CHB + 3) / 4; ++r) {
        int blk = r * 4 + wv;
        if (blk < CHB)
          gload_lds16(wn + (size_t)(blk * 64 + lane) * 8,
                      &wlds[buf ^ 1][blk * 512]);
      }
    }
    const int t = s / SPT;
    const int kh0 = (s - t * SPT) * KHC;
    const int dy = t / 3 - 1, dx = t - (t / 3) * 3 - 1;
    const int sb = lanebase + ((dy + 1) * COLS + (dx + 1)) * CIPAD + kh0 * 16;
#pragma unroll
    for (int khr = 0; khr < KHC; ++khr) {
      short8 bf = *(const short8*)&lds[sb + khr * 16];
#pragma unroll
      for (int j = 0; j < OCT; ++j) {
        short8 af =
            *(const short8*)&wlds[buf][(khr * OCT + j) * 512 + lane * 8];
        acc[j] =
            __builtin_amdgcn_mfma_f32_32x32x16_bf16(af, bf, acc[j], 0, 0, 0);
      }
    }
    __syncthreads();
    buf ^= 1;
  }

  // ---- epilogue -------------------------------------------------------
  {
    int row = py0 + wv * 2 + sr;
    int pxc = px0 + colp;
    us* ob = out + ((size_t)z * HW + (size_t)row * IMW + pxc) * out_cst + out_coff;
#pragma unroll
    for (int j = 0; j < OCT; ++j) {
#pragma unroll
      for (int hi = 0; hi < 4; ++hi) {
        int oc0 = j * 32 + hi * 8 + kq * 4;
        f32x4 bb = *(const f32x4*)&bias[oc0];
        float v0 = acc[j][4 * hi + 0] + bb[0];
        float v1 = acc[j][4 * hi + 1] + bb[1];
        float v2 = acc[j][4 * hi + 2] + bb[2];
        float v3 = acc[j][4 * hi + 3] + bb[3];
        if (LRELU) {
          v0 = v0 >= 0.f ? v0 : 0.1f * v0;
          v1 = v1 >= 0.f ? v1 : 0.1f * v1;
          v2 = v2 >= 0.f ? v2 : 0.1f * v2;
          v3 = v3 >= 0.f ? v3 : 0.1f * v3;
        }
        uint2 w;
        w.x = pk2(v0, v1);
        w.y = pk2(v2, v3);
        *(uint2*)&ob[oc0] = w;
      }
    }
  }
}

// ---------------------------------------------------------------------------
// 16x16x32 template (R4 structure: act-only LDS, weights global->reg from
// burst layout with register double-buffer). Used for the small convs + aw.
// ---------------------------------------------------------------------------
template <int CIN, int CST, int KPAD, int DIL, int G, int ZDIV, int CSUB,
          int RES, int OUTMODE, bool LRELU>
__global__ __launch_bounds__(256) void conv3x3_mfma(
    const us* __restrict__ in, const us* __restrict__ W2,
    const float* __restrict__ bias, void* __restrict__ out, int out_cst,
    int out_coff, float* __restrict__ outB, const float* __restrict__ res,
    int res_cst, int res_coff) {
  constexpr int OC = G * 16;
  constexpr int COLS = 16 + 2 * DIL;
  constexpr int ROWS = 8 + 2 * DIL;
  constexpr int HALO = ROWS * COLS;
  constexpr int CIPAD = KPAD + 8;
  constexpr int CH = KPAD / 8;
  constexpr int NKC = KPAD / 32;
  constexpr int GW0 = (G + 1) / 2;
  constexpr int NU = 9 * NKC;
  __shared__ alignas(16) short lds[HALO * CIPAD];

  const int z = blockIdx.z;
  const int bin = z / ZDIV;
  const int coff = (z % ZDIV) * CSUB;
  const int px0 = blockIdx.x * 16, py0 = blockIdx.y * 8;
  const int lane = threadIdx.x & 63;
  const int wv = threadIdx.x >> 6;
  const int m = lane & 15, q = lane >> 4;
  const int gh = wv & 1, rh = wv >> 1;
  const int goff = gh * GW0;

  f32x4 acc[GW0][4];
#pragma unroll
  for (int g = 0; g < GW0; ++g)
#pragma unroll
    for (int r = 0; r < 4; ++r) acc[g][r] = 0.f;

  for (int c = threadIdx.x; c < HALO * CH; c += 256) {
    int p = c / CH, cb = c - p * CH;
    int row = p / COLS, col = p - row * COLS;
    int gy = py0 + row - DIL, gx = px0 + col - DIL;
    bool ok = ((unsigned)gy < IMH) && ((unsigned)gx < IMW);
    int ci0 = cb * 8;
    const us* gp = in + ((size_t)bin * HW + (size_t)gy * IMW + gx) * CST + coff + ci0;
    if (CIN == KPAD) {
      short8 v = (short8)0;
      if (ok) v = *(const short8*)gp;
      *(short8*)&lds[p * CIPAD + ci0] = v;
    } else {
      uint2 h0; h0.x = 0; h0.y = 0;
      uint2 h1; h1.x = 0; h1.y = 0;
      if (ok && ci0 + 4 <= CIN) h0 = *(const uint2*)gp;
      if (ok && ci0 + 8 <= CIN) h1 = *(const uint2*)(gp + 4);
      *(uint2*)&lds[p * CIPAD + ci0] = h0;
      *(uint2*)&lds[p * CIPAD + ci0 + 4] = h1;
    }
  }
  __syncthreads();

  const us* wl = W2 + (size_t)lane * 8;
  short8 af[2][GW0];
#pragma unroll
  for (int g = 0; g < GW0; ++g)
    if (goff + g < G)
      af[0][g] = *(const short8*)(wl + (size_t)((goff + g) * NKC) * 512);

#pragma unroll
  for (int u = 0; u < NU; ++u) {
    const int t = u / NKC, kc = u - t * NKC;
    if (u + 1 < NU) {
      const int t1 = (u + 1) / NKC, kc1 = (u + 1) - t1 * NKC;
#pragma unroll
      for (int g = 0; g < GW0; ++g)
        if (goff + g < G)
          af[(u + 1) & 1][g] =
              *(const short8*)(wl + (size_t)((t1 * G + goff + g) * NKC + kc1) * 512);
    }
    const int dy = t / 3 - 1, dx = t - (t / 3) * 3 - 1;
    short8 bfr[4];
#pragma unroll
    for (int r = 0; r < 4; ++r) {
      int rr = rh * 4 + r + DIL + dy * DIL;
      int cc = m + DIL + dx * DIL;
      bfr[r] = *(const short8*)&lds[(rr * COLS + cc) * CIPAD + kc * 32 + q * 8];
    }
#pragma unroll
    for (int g = 0; g < GW0; ++g)
      if (goff + g < G)
#pragma unroll
        for (int r = 0; r < 4; ++r)
          acc[g][r] = __builtin_amdgcn_mfma_f32_16x16x32_bf16(af[u & 1][g], bfr[r],
                                                              acc[g][r], 0, 0, 0);
  }

#pragma unroll
  for (int g = 0; g < GW0; ++g) {
    if (goff + g < G) {
      int oc0 = (goff + g) * 16 + q * 4;
      f32x4 bb = *(const f32x4*)&bias[oc0];
#pragma unroll
      for (int r = 0; r < 4; ++r) {
        int py = py0 + rh * 4 + r;
        int px = px0 + m;
        size_t pix = (size_t)py * IMW + px;
        f32x4 v;
#pragma unroll
        for (int e = 0; e < 4; ++e) {
          float x = acc[g][r][e] + bb[e];
          if (LRELU) x = x >= 0.f ? x : 0.1f * x;
          v[e] = x;
        }
        if (RES == 1) {
          f32x4 rv = *(const f32x4*)&res[((size_t)z * HW + pix) * res_cst + oc0];
#pragma unroll
          for (int e = 0; e < 4; ++e) v[e] += rv[e];
        }
        if (RES == 2) {
#pragma unroll
          for (int e = 0; e < 4; ++e)
            v[e] += res[((size_t)z * res_cst + res_coff + oc0 + e) * HW + pix];
        }
        if (OUTMODE == 0 || OUTMODE == 3) {
          uint2 w;
          w.x = pk2(v[0], v[1]);
          w.y = pk2(v[2], v[3]);
          *(uint2*)&((us*)out)[((size_t)z * HW + pix) * out_cst + out_coff + oc0] = w;
        }
        if (OUTMODE == 2)
          *(f32x4*)&((float*)out)[((size_t)z * HW + pix) * out_cst + oc0] = v;
        if (OUTMODE == 3)
          *(f32x4*)&outB[((size_t)z * HW + pix) * 32 + oc0] = v;
      }
    }
  }
}

// ---------------------------------------------------------------------------
// Deformable attention. valp [6][HW][32] bf16; off [2][HW][96] bf16;
// aw [2][HW][48] f32; out attn [2][HW][32] bf16.
// Parallelized over (pixel, head): tid&3 = head, tid>>2 = pixel-in-block.
// ---------------------------------------------------------------------------
__global__ __launch_bounds__(256) void deform_attn(
    const us* __restrict__ valp, const us* __restrict__ off,
    const float* __restrict__ aw, us* __restrict__ outp) {
  int tid = threadIdx.x;
  int hh = tid & 3;
  int pix = blockIdx.x * 64 + (tid >> 2);
  int b = blockIdx.y;
  int px = pix & (IMW - 1), py = pix >> 8;
  float refx = ((float)px + 0.5f) * (1.0f / IMW);
  float refy = ((float)py + 0.5f) * (1.0f / IMH);

  ushortx8 o8[3];
  {
    const ushortx8* ob =
        (const ushortx8*)(off + ((size_t)b * HW + pix) * 96 + hh * 24);
#pragma unroll
    for (int j = 0; j < 3; ++j) o8[j] = ob[j];
  }
  f32x4 a4[3];
  {
    const f32x4* ab = (const f32x4*)(aw + ((size_t)b * HW + pix) * 48 + hh * 12);
#pragma unroll
    for (int j = 0; j < 3; ++j) a4[j] = ab[j];
  }

  float wv[12];
  float mx = -1e30f;
#pragma unroll
  for (int lp = 0; lp < 12; ++lp) {
    wv[lp] = a4[lp >> 2][lp & 3];
    mx = fmaxf(mx, wv[lp]);
  }
  float s = 0.f;
#pragma unroll
  for (int lp = 0; lp < 12; ++lp) {
    wv[lp] = __expf(wv[lp] - mx);
    s += wv[lp];
  }
  float inv = 1.f / s;

  float acc[8] = {0.f, 0.f, 0.f, 0.f, 0.f, 0.f, 0.f, 0.f};
#pragma unroll 1
  for (int l = 0; l < 3; ++l) {
    const us* vbase = valp + ((size_t)(b * 3 + l) * HW) * 32 + hh * 8;
#pragma unroll
    for (int p = 0; p < 4; ++p) {
      int ch = l * 8 + p * 2;
      float ox = u2f(o8[ch >> 3][ch & 7]);
      float oy = u2f(o8[(ch + 1) >> 3][(ch + 1) & 7]);
      float x = (refx + ox * (1.0f / IMW)) * (float)IMW - 0.5f;
      float y = (refy + oy * (1.0f / IMH)) * (float)IMH - 0.5f;
      float x0f = floorf(x), y0f = floorf(y);
      float lx = x - x0f, ly = y - y0f;
      int x0 = (int)x0f, y0 = (int)y0f;
      float a = wv[l * 4 + p] * inv;
      float cw[4] = {(1.f - lx) * (1.f - ly) * a, lx * (1.f - ly) * a,
                     (1.f - lx) * ly * a, lx * ly * a};
#pragma unroll
      for (int k = 0; k < 4; ++k) {
        int xi = x0 + (k & 1), yi = y0 + (k >> 1);
        if ((unsigned)xi < IMW && (unsigned)yi < IMH) {
          const ushortx8 u = *(const ushortx8*)(vbase + (size_t)(yi * IMW + xi) * 32);
          float wgt = cw[k];
#pragma unroll
          for (int dd = 0; dd < 8; ++dd) acc[dd] = fmaf(wgt, u2f(u[dd]), acc[dd]);
        }
      }
    }
  }
  ushortx8 sv;
#pragma unroll
  for (int dd = 0; dd < 8; ++dd) sv[dd] = f2bu(acc[dd]);
  *(ushortx8*)(outp + ((size_t)b * HW + pix) * 32 + hh * 8) = sv;
}

// ---------------------------------------------------------------------------
// srcframe[:,1] fp32 NCHW -> out1b NHWC-64 ch32..63 (bf16)
// ---------------------------------------------------------------------------
__global__ __launch_bounds__(256) void copy_src(const float* __restrict__ src,
                                                unsigned* __restrict__ out1b) {
  int pix = blockIdx.x * 256 + threadIdx.x;
  int b = blockIdx.y;
  const float* s = src + ((size_t)(b * 3 + 1) * 32) * HW + pix;
  unsigned u[16];
#pragma unroll
  for (int j = 0; j < 16; ++j)
    u[j] = pk2(s[(size_t)(2 * j) * HW], s[(size_t)(2 * j + 1) * HW]);
  unsigned* d = out1b + ((size_t)b * HW + pix) * 32 + 16;
#pragma unroll
  for (int j = 0; j < 4; ++j) {
    uint4 w;
    w.x = u[4 * j]; w.y = u[4 * j + 1]; w.z = u[4 * j + 2]; w.w = u[4 * j + 3];
    *(uint4*)&d[4 * j] = w;
  }
}

// ---------------------------------------------------------------------------
// final 1x1 conv + lrelu: out2 NHWC-32 f32 -> d_out fp32 NCHW
// ---------------------------------------------------------------------------
__global__ __launch_bounds__(256) void conv1x1_fu(
    const float* __restrict__ in, const float* __restrict__ wgt,
    const float* __restrict__ bias, float* __restrict__ out) {
  int pix = blockIdx.x * 256 + threadIdx.x;
  int b = blockIdx.y;
  float vin[32];
  {
    const f32x4* s = (const f32x4*)(in + ((size_t)b * HW + pix) * 32);
#pragma unroll
    for (int j = 0; j < 8; ++j) {
      f32x4 v = s[j];
#pragma unroll
      for (int e = 0; e < 4; ++e) vin[4 * j + e] = v[e];
    }
  }
#pragma unroll 1
  for (int oc = 0; oc < 32; ++oc) {
    float a = bias[oc];
#pragma unroll
    for (int ci = 0; ci < 32; ++ci) a = fmaf(wgt[oc * 32 + ci], vin[ci], a);
    a = a >= 0.f ? a : 0.1f * a;
    out[((size_t)b * 32 + oc) * HW + pix] = a;
  }
}

// ---------------------------------------------------------------------------
extern "C" void kernel_launch(void* const* d_in, const int* in_sizes, int n_in,
                              void* d_out, int out_size, void* d_ws, size_t ws_size,
                              hipStream_t stream) {
  (void)in_sizes; (void)n_in; (void)out_size;
  // Footprint: 25,614,592 floats = 102.46 MB (same as prior rounds, known OK).
  if (ws_size < 25614592ull * 4) return;

  const float* frame = (const float*)d_in[0];
  const float* srcframe = (const float*)d_in[1];
  const float* flowf = (const float*)d_in[2];
  const float* flowb = (const float*)d_in[3];

  float* ws = (float*)d_ws;
  us* wsu = (us*)d_ws;

  // bf16 weights, offsets in shorts (end 373,248 = 186,624 fl)
  static const int w2off[9] = {0,      110592, 193536, 202752, 285696,
                               327168, 336384, 345600, 364032};
  // Activation slots (float offsets):
  //  S1 @   186,624 (6,291,456): fnhwc -> offb -> ff1out
  //  S2 @ 6,478,080 (6,553,600): qk -> V -> awb(f32) -> out1b
  //  S3 @13,031,680 (6,291,456): Q -> attn + convout -> out2(f32)
  //  S4 @19,323,136 (6,291,456): Vp -> out1f(f32)
  us* fnhwc = (us*)(ws + 186624);
  unsigned* qk_u = (unsigned*)(ws + 6478080);
  us* qk = (us*)qk_u;
  us* Q = (us*)(ws + 13031680);
  us* V = (us*)(ws + 6478080);
  us* Vp = (us*)(ws + 19323136);
  us* offb = (us*)(ws + 186624);
  float* awb = (float*)(ws + 6478080);
  us* attn = (us*)(ws + 13031680);
  us* convout = (us*)(ws + 13031680 + 2097152);
  us* out1b = (us*)(ws + 6478080);
  unsigned* out1b_u = (unsigned*)out1b;
  float* out1f = (float*)(ws + 19323136);
  us* ff1out = (us*)(ws + 186624);
  float* out2 = (float*)(ws + 13031680);

  // 1) weight prep (LAY=1 m32-chunk layout for qk/v/off; burst for the rest)
  {
    PrepArgs pa;
    static const int srcidx[9] = {4, 6, 8, 10, 12, 14, 16, 18, 20};
    static const int OCs[9] = {96, 96, 32, 96, 48, 32, 32, 32, 32};
    static const int CINs[9] = {100, 96, 32, 96, 96, 32, 32, 64, 32};
    static const int KPADs[9] = {128, 96, 32, 96, 96, 32, 32, 64, 32};
    static const int LAYs[9] = {1, 1, 0, 1, 0, 0, 0, 0, 0};
    for (int i = 0; i < 9; ++i) {
      pa.src[i] = (const float*)d_in[srcidx[i]];
      pa.dst[i] = wsu + w2off[i];
      pa.OC[i] = OCs[i];
      pa.CIN[i] = CINs[i];
      pa.KPAD[i] = KPADs[i];
      pa.LAY[i] = LAYs[i];
    }
    prep_weights<<<dim3(432, 9), 256, 0, stream>>>(pa);
  }

  // 2) frame -> NHWC bf16
  frame_to_nhwc<<<dim3(256, 2), 256, 0, stream>>>(frame, (unsigned*)fnhwc);

  // 3) qk_in NHWC-100
  build_qkin<<<dim3(256, 2), 256, 0, stream>>>(fnhwc, flowf, flowb, qk_u);

  dim3 cg2(16, 32, 2);

  // 4) qureys = lrelu(conv_qk)  100->96  (m32: KPAD=128, OCT=3, KHC=4)
  conv3x3_m32<100, 100, 128, 3, 4, true><<<cg2, 256, 0, stream>>>(
      qk, wsu + w2off[0], (const float*)d_in[5], Q, 96, 0);

  // 5) value = conv_v(fnhwc) 96->96  (m32: KPAD=96, OCT=3, KHC=6)
  conv3x3_m32<96, 96, 96, 3, 6, false><<<cg2, 256, 0, stream>>>(
      fnhwc, wsu + w2off[1], (const float*)d_in[7], V, 96, 0);

  // 6) val = conv_vp per (b,l) 32->32 -> Vp [6][HW][32]
  conv3x3_mfma<32, 96, 32, 1, 2, 3, 32, 0, 0, false><<<dim3(16, 32, 6), 256, 0, stream>>>(
      V, wsu + w2off[2], (const float*)d_in[9], Vp, 32, 0, nullptr, nullptr, 0, 0);

  // 7) off = conv_off(Q) 96->96 (m32)  (S1; fnhwc dead)
  conv3x3_m32<96, 96, 96, 3, 6, false><<<cg2, 256, 0, stream>>>(
      Q, wsu + w2off[3], (const float*)d_in[11], offb, 96, 0);

  // 8) aw = conv_aw(Q) 96->48 f32 NHWC (S2; V dead)  G=3
  conv3x3_mfma<96, 96, 96, 1, 3, 1, 0, 0, 2, false><<<cg2, 256, 0, stream>>>(
      Q, wsu + w2off[4], (const float*)d_in[13], awb, 48, 0, nullptr, nullptr, 0, 0);

  // 9) deformable attention -> attn (S3; Q dead)  [(pixel,head)-parallel]
  deform_attn<<<dim3(1024, 2), 256, 0, stream>>>(Vp, offb, awb, attn);

  // 10) conv_out(attn) 32->32 (S3 tail)
  conv3x3_mfma<32, 32, 32, 1, 2, 1, 0, 0, 0, false><<<cg2, 256, 0, stream>>>(
      attn, wsu + w2off[5], (const float*)d_in[15], convout, 32, 0, nullptr, nullptr, 0, 0);

  // 11) out1 = conv_ffd(convout) + frame[:,1] -> out1b(NHWC-64 bf16) + out1f(f32)
  conv3x3_mfma<32, 32, 32, 1, 2, 1, 0, 2, 3, false><<<cg2, 256, 0, stream>>>(
      convout, wsu + w2off[6], (const float*)d_in[17], out1b, 64, 0, out1f, frame, 96, 32);

  // 12) srcframe[:,1] -> out1b ch32..63
  copy_src<<<dim3(256, 2), 256, 0, stream>>>(srcframe, out1b_u);

  // 13) ff1 = lrelu(conv dil=2 on out1b 64ch) -> ff1out (S1; offb dead)
  conv3x3_mfma<64, 64, 64, 2, 2, 1, 0, 0, 0, true><<<cg2, 256, 0, stream>>>(
      out1b, wsu + w2off[7], (const float*)d_in[19], ff1out, 32, 0, nullptr, nullptr, 0, 0);

  // 14) out2 = conv_ff2(ff1out) + out1f -> f32 NHWC-32 (S3; attn/convout dead)
  conv3x3_mfma<32, 32, 32, 1, 2, 1, 0, 1, 2, false><<<cg2, 256, 0, stream>>>(
      ff1out, wsu + w2off[8], (const float*)d_in[21], out2, 32, 0, nullptr, out1f, 32, 0);

  // 15) out = lrelu(conv_fu 1x1(out2)) -> fp32 NCHW d_out
  conv1x1_fu<<<dim3(256, 2), 256, 0, stream>>>(out2, (const float*)d_in[22],
                                               (const float*)d_in[23], (float*)d_out);
}

// Round 7
// 461.307 us; speedup vs baseline: 1.1084x; 1.0081x over previous
//
#include <hip/hip_runtime.h>
#include <hip/hip_bf16.h>

typedef __hip_bfloat16 bf16;
typedef unsigned short us;
typedef unsigned int u32;
typedef __attribute__((ext_vector_type(8))) short short8;
typedef __attribute__((ext_vector_type(8))) unsigned short ushortx8;
typedef __attribute__((ext_vector_type(2))) float f32x2;
typedef __attribute__((ext_vector_type(4))) float f32x4;
typedef __attribute__((ext_vector_type(16))) float f32x16;

#define HW 65536
#define IMW 256
#define IMH 256

static __device__ __forceinline__ float u2f(us u) {
  return __uint_as_float(((unsigned)u) << 16);
}
static __device__ __forceinline__ us f2bu(float x) {
  bf16 h = __float2bfloat16(x);
  return *reinterpret_cast<us*>(&h);
}
static __device__ __forceinline__ unsigned pk2(float a, float b) {
  return (unsigned)f2bu(a) | ((unsigned)f2bu(b) << 16);
}

// async global->LDS 16B: per-lane global src, wave-uniform LDS dest
static __device__ __forceinline__ void gload_lds16(const void* g, void* l) {
  __builtin_amdgcn_global_load_lds(
      (const __attribute__((address_space(1))) u32*)g,
      (__attribute__((address_space(3))) u32*)l, 16, 0, 0);
}

// ---------------------------------------------------------------------------
// Weight prep. Two layouts:
// LAY=0 (burst, for 16x16 template): [t][g][kc][q][m][8]; oc=g*16+m, k=kc*32+q*8+e
// LAY=1 (m32 chunks, for 32x32 template): [t][kh][j][lane][8];
//        oc=j*32+(lane&31), k=kh*16+(lane>>5)*8+e
// Both zero-pad K to KPAD.
// ---------------------------------------------------------------------------
struct PrepArgs {
  const float* src[9];
  us* dst[9];
  int OC[9], CIN[9], KPAD[9], LAY[9];
};

__global__ __launch_bounds__(256) void prep_weights(PrepArgs a) {
  int j = blockIdx.y;
  int n = blockIdx.x * 256 + threadIdx.x;
  int OC = a.OC[j], CIN = a.CIN[j], KPAD = a.KPAD[j];
  int tot = 9 * OC * KPAD;
  if (n >= tot) return;
  int oc, k;
  if (a.LAY[j] == 0) {
    int G = OC >> 4, NKC = KPAD >> 5;
    int e = n & 7;
    int m = (n >> 3) & 15;
    int q = (n >> 7) & 3;
    int rest = n >> 9;          // (t*G + g)*NKC + kc
    int kc = rest % NKC;
    int tg = rest / NKC;
    int g = tg % G;
    int t = tg / G;
    oc = g * 16 + m;
    k = kc * 32 + q * 8 + e;
    float v = (k < CIN) ? a.src[j][(size_t)(oc * CIN + k) * 9 + t] : 0.f;
    a.dst[j][n] = f2bu(v);
  } else {
    int OCT = OC >> 5, KH = KPAD >> 4;
    int e = n & 7;
    int l = (n >> 3) & 63;
    int rest = n >> 9;          // ((t*KH + kh)*OCT + jt)
    int jt = rest % OCT;
    int u = rest / OCT;
    int kh = u % KH;
    int t = u / KH;
    oc = jt * 32 + (l & 31);
    k = kh * 16 + (l >> 5) * 8 + e;
    float v = (k < CIN) ? a.src[j][(size_t)(oc * CIN + k) * 9 + t] : 0.f;
    a.dst[j][n] = f2bu(v);
  }
}

// ---------------------------------------------------------------------------
// frame fp32 NCHW [b][96][HW] -> NHWC bf16 [b][HW][96]
// ---------------------------------------------------------------------------
__global__ __launch_bounds__(256) void frame_to_nhwc(const float* __restrict__ frame,
                                                     unsigned* __restrict__ fn) {
  int pix = blockIdx.x * 256 + threadIdx.x;
  int b = blockIdx.y;
  const float* s = frame + (size_t)b * 96 * HW + pix;
  unsigned u[48];
#pragma unroll
  for (int j = 0; j < 48; ++j)
    u[j] = pk2(s[(size_t)(2 * j) * HW], s[(size_t)(2 * j + 1) * HW]);
  unsigned* d = fn + ((size_t)b * HW + pix) * 48;
#pragma unroll
  for (int j = 0; j < 12; ++j) {
    uint4 w;
    w.x = u[4 * j]; w.y = u[4 * j + 1]; w.z = u[4 * j + 2]; w.w = u[4 * j + 3];
    *(uint4*)&d[4 * j] = w;
  }
}

// ---------------------------------------------------------------------------
// qk_in build from NHWC frame: warp01 | frame[:,1] | warp21 | flows
// -> qk NHWC bf16 [b][HW][100]
// ---------------------------------------------------------------------------
static __device__ void warp_nhwc(const us* __restrict__ fn, size_t bbase, int coff,
                                 float x, float y, unsigned* uo) {
  float x0f = floorf(x), y0f = floorf(y);
  float lx = x - x0f, ly = y - y0f;
  int x0 = (int)x0f, y0 = (int)y0f;
  float wt[4] = {(1.f - lx) * (1.f - ly), lx * (1.f - ly), (1.f - lx) * ly, lx * ly};
  float acc[32] = {};
#pragma unroll
  for (int k = 0; k < 4; ++k) {
    int xi = x0 + (k & 1), yi = y0 + (k >> 1);
    if ((unsigned)xi < IMW && (unsigned)yi < IMH) {
      const ushortx8* s =
          (const ushortx8*)(fn + (bbase + (size_t)yi * IMW + xi) * 96 + coff);
      float w = wt[k];
#pragma unroll
      for (int cj = 0; cj < 4; ++cj) {
        ushortx8 vv = s[cj];
#pragma unroll
        for (int e = 0; e < 8; ++e)
          acc[cj * 8 + e] = fmaf(w, u2f(vv[e]), acc[cj * 8 + e]);
      }
    }
  }
#pragma unroll
  for (int j = 0; j < 16; ++j) uo[j] = pk2(acc[2 * j], acc[2 * j + 1]);
}

__global__ __launch_bounds__(256) void build_qkin(
    const us* __restrict__ fn, const float* __restrict__ flowf,
    const float* __restrict__ flowb, unsigned* __restrict__ qk) {
  int pix = blockIdx.x * 256 + threadIdx.x;
  int b = blockIdx.y;
  int px = pix & 255, py = pix >> 8;

  float fbx = flowb[((size_t)(b * 2 + 0) * 2 + 0) * HW + pix];
  float fby = flowb[((size_t)(b * 2 + 0) * 2 + 1) * HW + pix];
  float ffx = flowf[((size_t)(b * 2 + 1) * 2 + 0) * HW + pix];
  float ffy = flowf[((size_t)(b * 2 + 1) * 2 + 1) * HW + pix];

  unsigned u[50];
  {
    const unsigned* s = (const unsigned*)(fn + ((size_t)b * HW + pix) * 96);
#pragma unroll
    for (int j = 0; j < 16; ++j) u[16 + j] = s[16 + j];
  }
  u[48] = pk2(ffx, ffy);
  u[49] = pk2(fbx, fby);

  warp_nhwc(fn, (size_t)b * HW, 0, (float)px + fbx, (float)py + fby, &u[0]);
  warp_nhwc(fn, (size_t)b * HW, 64, (float)px + ffx, (float)py + ffy, &u[32]);

  unsigned* qb = qk + ((size_t)b * HW + pix) * 50;
#pragma unroll
  for (int j = 0; j < 25; ++j) {
    uint2 t;
    t.x = u[2 * j];
    t.y = u[2 * j + 1];
    *(uint2*)(qb + 2 * j) = t;
  }
}

// ---------------------------------------------------------------------------
// 32x32x16-MFMA implicit-GEMM 3x3 conv for OC multiple of 32 (r6, verified).
// ---------------------------------------------------------------------------
template <int CIN, int CST, int KPAD, int OCT, int KHC, bool LRELU>
__global__ __launch_bounds__(256) void conv3x3_m32(
    const us* __restrict__ in, const us* __restrict__ W2,
    const float* __restrict__ bias, us* __restrict__ out, int out_cst,
    int out_coff) {
  constexpr int COLS = 18, ROWS = 10, HALO = COLS * ROWS;
  constexpr int CIPAD = KPAD + 8;
  constexpr int CH = KPAD / 8;
  constexpr int KH = KPAD / 16;
  constexpr int SPT = KH / KHC;          // stages per tap
  constexpr int NSTG = 9 * SPT;
  constexpr int CHB = KHC * OCT;         // 1KB blocks per weight chunk
  __shared__ alignas(16) short lds[HALO * CIPAD];
  __shared__ alignas(16) short wlds[2][CHB * 512];

  const int z = blockIdx.z;
  const int px0 = blockIdx.x * 16, py0 = blockIdx.y * 8;
  const int lane = threadIdx.x & 63;
  const int wv = threadIdx.x >> 6;
  const int n = lane & 31;
  const int sr = n >> 4;
  const int colp = n & 15;
  const int kq = lane >> 5;

  f32x16 acc[OCT];
#pragma unroll
  for (int j = 0; j < OCT; ++j) acc[j] = 0.f;

  // ---- stage whole-K NHWC halo tile into LDS [pos][ci], coalesced ----
  for (int c = threadIdx.x; c < HALO * CH; c += 256) {
    int p = c / CH, cb = c - p * CH;
    int row = p / COLS, col = p - row * COLS;
    int gy = py0 + row - 1, gx = px0 + col - 1;
    bool ok = ((unsigned)gy < IMH) && ((unsigned)gx < IMW);
    int ci0 = cb * 8;
    const us* gp = in + ((size_t)z * HW + (size_t)gy * IMW + gx) * CST + ci0;
    if (CIN == KPAD) {
      short8 v = (short8)0;
      if (ok) v = *(const short8*)gp;
      *(short8*)&lds[p * CIPAD + ci0] = v;
    } else {
      uint2 h0; h0.x = 0; h0.y = 0;
      uint2 h1; h1.x = 0; h1.y = 0;
      if (ok && ci0 + 4 <= CIN) h0 = *(const uint2*)gp;
      if (ok && ci0 + 8 <= CIN) h1 = *(const uint2*)(gp + 4);
      *(uint2*)&lds[p * CIPAD + ci0] = h0;
      *(uint2*)&lds[p * CIPAD + ci0 + 4] = h1;
    }
  }

  // ---- stage weight chunk 0 (async, drained by the barrier) ----------
#pragma unroll
  for (int r = 0; r < (CHB + 3) / 4; ++r) {
    int blk = r * 4 + wv;
    if (blk < CHB)
      gload_lds16(W2 + (size_t)(blk * 64 + lane) * 8, &wlds[0][blk * 512]);
  }
  __syncthreads();

  const int lanebase = ((wv * 2 + sr) * COLS + colp) * CIPAD + kq * 8;

  int buf = 0;
#pragma unroll 1
  for (int s = 0; s < NSTG; ++s) {
    if (s + 1 < NSTG) {
      const us* wn = W2 + (size_t)(s + 1) * (CHB * 512);
#pragma unroll
      for (int r = 0; r < (CHB + 3) / 4; ++r) {
        int blk = r * 4 + wv;
        if (blk < CHB)
          gload_lds16(wn + (size_t)(blk * 64 + lane) * 8,
                      &wlds[buf ^ 1][blk * 512]);
      }
    }
    const int t = s / SPT;
    const int kh0 = (s - t * SPT) * KHC;
    const int dy = t / 3 - 1, dx = t - (t / 3) * 3 - 1;
    const int sb = lanebase + ((dy + 1) * COLS + (dx + 1)) * CIPAD + kh0 * 16;
#pragma unroll
    for (int khr = 0; khr < KHC; ++khr) {
      short8 bf = *(const short8*)&lds[sb + khr * 16];
#pragma unroll
      for (int j = 0; j < OCT; ++j) {
        short8 af =
            *(const short8*)&wlds[buf][(khr * OCT + j) * 512 + lane * 8];
        acc[j] =
            __builtin_amdgcn_mfma_f32_32x32x16_bf16(af, bf, acc[j], 0, 0, 0);
      }
    }
    __syncthreads();
    buf ^= 1;
  }

  // ---- epilogue -------------------------------------------------------
  {
    int row = py0 + wv * 2 + sr;
    int pxc = px0 + colp;
    us* ob = out + ((size_t)z * HW + (size_t)row * IMW + pxc) * out_cst + out_coff;
#pragma unroll
    for (int j = 0; j < OCT; ++j) {
#pragma unroll
      for (int hi = 0; hi < 4; ++hi) {
        int oc0 = j * 32 + hi * 8 + kq * 4;
        f32x4 bb = *(const f32x4*)&bias[oc0];
        float v0 = acc[j][4 * hi + 0] + bb[0];
        float v1 = acc[j][4 * hi + 1] + bb[1];
        float v2 = acc[j][4 * hi + 2] + bb[2];
        float v3 = acc[j][4 * hi + 3] + bb[3];
        if (LRELU) {
          v0 = v0 >= 0.f ? v0 : 0.1f * v0;
          v1 = v1 >= 0.f ? v1 : 0.1f * v1;
          v2 = v2 >= 0.f ? v2 : 0.1f * v2;
          v3 = v3 >= 0.f ? v3 : 0.1f * v3;
        }
        uint2 w;
        w.x = pk2(v0, v1);
        w.y = pk2(v2, v3);
        *(uint2*)&ob[oc0] = w;
      }
    }
  }
}

// ---------------------------------------------------------------------------
// 16x16x32 template (R4 structure). Used for the small convs + aw.
// ---------------------------------------------------------------------------
template <int CIN, int CST, int KPAD, int DIL, int G, int ZDIV, int CSUB,
          int RES, int OUTMODE, bool LRELU>
__global__ __launch_bounds__(256) void conv3x3_mfma(
    const us* __restrict__ in, const us* __restrict__ W2,
    const float* __restrict__ bias, void* __restrict__ out, int out_cst,
    int out_coff, float* __restrict__ outB, const float* __restrict__ res,
    int res_cst, int res_coff) {
  constexpr int OC = G * 16;
  constexpr int COLS = 16 + 2 * DIL;
  constexpr int ROWS = 8 + 2 * DIL;
  constexpr int HALO = ROWS * COLS;
  constexpr int CIPAD = KPAD + 8;
  constexpr int CH = KPAD / 8;
  constexpr int NKC = KPAD / 32;
  constexpr int GW0 = (G + 1) / 2;
  constexpr int NU = 9 * NKC;
  __shared__ alignas(16) short lds[HALO * CIPAD];

  const int z = blockIdx.z;
  const int bin = z / ZDIV;
  const int coff = (z % ZDIV) * CSUB;
  const int px0 = blockIdx.x * 16, py0 = blockIdx.y * 8;
  const int lane = threadIdx.x & 63;
  const int wv = threadIdx.x >> 6;
  const int m = lane & 15, q = lane >> 4;
  const int gh = wv & 1, rh = wv >> 1;
  const int goff = gh * GW0;

  f32x4 acc[GW0][4];
#pragma unroll
  for (int g = 0; g < GW0; ++g)
#pragma unroll
    for (int r = 0; r < 4; ++r) acc[g][r] = 0.f;

  for (int c = threadIdx.x; c < HALO * CH; c += 256) {
    int p = c / CH, cb = c - p * CH;
    int row = p / COLS, col = p - row * COLS;
    int gy = py0 + row - DIL, gx = px0 + col - DIL;
    bool ok = ((unsigned)gy < IMH) && ((unsigned)gx < IMW);
    int ci0 = cb * 8;
    const us* gp = in + ((size_t)bin * HW + (size_t)gy * IMW + gx) * CST + coff + ci0;
    if (CIN == KPAD) {
      short8 v = (short8)0;
      if (ok) v = *(const short8*)gp;
      *(short8*)&lds[p * CIPAD + ci0] = v;
    } else {
      uint2 h0; h0.x = 0; h0.y = 0;
      uint2 h1; h1.x = 0; h1.y = 0;
      if (ok && ci0 + 4 <= CIN) h0 = *(const uint2*)gp;
      if (ok && ci0 + 8 <= CIN) h1 = *(const uint2*)(gp + 4);
      *(uint2*)&lds[p * CIPAD + ci0] = h0;
      *(uint2*)&lds[p * CIPAD + ci0 + 4] = h1;
    }
  }
  __syncthreads();

  const us* wl = W2 + (size_t)lane * 8;
  short8 af[2][GW0];
#pragma unroll
  for (int g = 0; g < GW0; ++g)
    if (goff + g < G)
      af[0][g] = *(const short8*)(wl + (size_t)((goff + g) * NKC) * 512);

#pragma unroll
  for (int u = 0; u < NU; ++u) {
    const int t = u / NKC, kc = u - t * NKC;
    if (u + 1 < NU) {
      const int t1 = (u + 1) / NKC, kc1 = (u + 1) - t1 * NKC;
#pragma unroll
      for (int g = 0; g < GW0; ++g)
        if (goff + g < G)
          af[(u + 1) & 1][g] =
              *(const short8*)(wl + (size_t)((t1 * G + goff + g) * NKC + kc1) * 512);
    }
    const int dy = t / 3 - 1, dx = t - (t / 3) * 3 - 1;
    short8 bfr[4];
#pragma unroll
    for (int r = 0; r < 4; ++r) {
      int rr = rh * 4 + r + DIL + dy * DIL;
      int cc = m + DIL + dx * DIL;
      bfr[r] = *(const short8*)&lds[(rr * COLS + cc) * CIPAD + kc * 32 + q * 8];
    }
#pragma unroll
    for (int g = 0; g < GW0; ++g)
      if (goff + g < G)
#pragma unroll
        for (int r = 0; r < 4; ++r)
          acc[g][r] = __builtin_amdgcn_mfma_f32_16x16x32_bf16(af[u & 1][g], bfr[r],
                                                              acc[g][r], 0, 0, 0);
  }

#pragma unroll
  for (int g = 0; g < GW0; ++g) {
    if (goff + g < G) {
      int oc0 = (goff + g) * 16 + q * 4;
      f32x4 bb = *(const f32x4*)&bias[oc0];
#pragma unroll
      for (int r = 0; r < 4; ++r) {
        int py = py0 + rh * 4 + r;
        int px = px0 + m;
        size_t pix = (size_t)py * IMW + px;
        f32x4 v;
#pragma unroll
        for (int e = 0; e < 4; ++e) {
          float x = acc[g][r][e] + bb[e];
          if (LRELU) x = x >= 0.f ? x : 0.1f * x;
          v[e] = x;
        }
        if (RES == 1) {
          f32x4 rv = *(const f32x4*)&res[((size_t)z * HW + pix) * res_cst + oc0];
#pragma unroll
          for (int e = 0; e < 4; ++e) v[e] += rv[e];
        }
        if (RES == 2) {
#pragma unroll
          for (int e = 0; e < 4; ++e)
            v[e] += res[((size_t)z * res_cst + res_coff + oc0 + e) * HW + pix];
        }
        if (OUTMODE == 0 || OUTMODE == 3) {
          uint2 w;
          w.x = pk2(v[0], v[1]);
          w.y = pk2(v[2], v[3]);
          *(uint2*)&((us*)out)[((size_t)z * HW + pix) * out_cst + out_coff + oc0] = w;
        }
        if (OUTMODE == 2)
          *(f32x4*)&((float*)out)[((size_t)z * HW + pix) * out_cst + oc0] = v;
        if (OUTMODE == 3)
          *(f32x4*)&outB[((size_t)z * HW + pix) * 32 + oc0] = v;
      }
    }
  }
}

// ---------------------------------------------------------------------------
// Deformable attention v3. valp [6][HW][32] bf16; off [2][HW][96] bf16;
// aw [2][HW][48] f32; out attn [2][HW][32] bf16.
// Thread = (pixel, head, half): tid&1 = half (6 of 12 (l,p) points each),
// (tid>>1)&3 = head, tid>>3 = pixel-in-block (32 px/block).
// Softmax max/sum and the final 8-ch accumulator are combined across the
// lane pair via __shfl_xor(.,1); lane half==0 writes the 16B result.
// Coords use x = px + ox (== (refx+ox/W)*W-0.5); corners are reached from
// one base pointer with constant offsets + precomputed validity bools.
// ---------------------------------------------------------------------------
__global__ __launch_bounds__(256) void deform_attn(
    const us* __restrict__ valp, const us* __restrict__ off,
    const float* __restrict__ aw, us* __restrict__ outp) {
  int tid = threadIdx.x;
  int half = tid & 1;
  int hh = (tid >> 1) & 3;
  int pix = blockIdx.x * 32 + (tid >> 3);
  int b = blockIdx.y;
  int px = pix & (IMW - 1), py = pix >> 8;

  // own half's 12 offset shorts (24B, 8B-aligned)
  us os[12];
  {
    const uint2* ob = (const uint2*)(off + ((size_t)b * HW + pix) * 96 +
                                     hh * 24 + half * 12);
    uint2 a0 = ob[0], a1 = ob[1], a2 = ob[2];
    *(uint2*)&os[0] = a0;
    *(uint2*)&os[4] = a1;
    *(uint2*)&os[8] = a2;
  }
  // own half's 6 attention logits (24B, 8B-aligned)
  float wv[6];
  {
    const f32x2* ab = (const f32x2*)(aw + ((size_t)b * HW + pix) * 48 +
                                     hh * 12 + half * 6);
    f32x2 a0 = ab[0], a1 = ab[1], a2 = ab[2];
    wv[0] = a0.x; wv[1] = a0.y; wv[2] = a1.x;
    wv[3] = a1.y; wv[4] = a2.x; wv[5] = a2.y;
  }

  // pairwise softmax
  float m6 = wv[0];
#pragma unroll
  for (int i = 1; i < 6; ++i) m6 = fmaxf(m6, wv[i]);
  float mx = fmaxf(m6, __shfl_xor(m6, 1));
  float s6 = 0.f;
#pragma unroll
  for (int i = 0; i < 6; ++i) {
    wv[i] = __expf(wv[i] - mx);
    s6 += wv[i];
  }
  float inv = 1.f / (s6 + __shfl_xor(s6, 1));

  f32x2 acc2[4];
#pragma unroll
  for (int j = 0; j < 4; ++j) acc2[j] = 0.f;

#pragma unroll
  for (int i = 0; i < 6; ++i) {
    int pp = half * 6 + i;          // global (l,p) pair index
    int l = pp >> 2;
    const us* vbase = valp + ((size_t)(b * 3 + l) * HW) * 32 + hh * 8;
    float x = (float)px + u2f(os[2 * i]);
    float y = (float)py + u2f(os[2 * i + 1]);
    float x0f = floorf(x), y0f = floorf(y);
    float lx = x - x0f, ly = y - y0f;
    int x0 = (int)x0f, y0 = (int)y0f;
    bool vx0 = (unsigned)x0 < IMW, vx1 = (unsigned)(x0 + 1) < IMW;
    bool vy0 = (unsigned)y0 < IMH, vy1 = (unsigned)(y0 + 1) < IMH;
    float a = wv[i] * inv;
    float ax0 = (1.f - lx) * a, ax1 = lx * a;
    float w00 = ax0 * (1.f - ly), w01 = ax1 * (1.f - ly);
    float w10 = ax0 * ly, w11 = ax1 * ly;
    const us* p00 = vbase + (size_t)((long)(y0 * IMW + x0)) * 32;
#pragma unroll
    for (int c = 0; c < 4; ++c) {
      bool ok = (c & 1 ? vx1 : vx0) && (c & 2 ? vy1 : vy0);
      float w = (c == 0) ? w00 : (c == 1) ? w01 : (c == 2) ? w10 : w11;
      const us* p = p00 + (c & 1) * 32 + (c >> 1) * (IMW * 32);
      if (ok) {
        uint4 uu = *(const uint4*)p;
        unsigned uarr[4] = {uu.x, uu.y, uu.z, uu.w};
#pragma unroll
        for (int j = 0; j < 4; ++j) {
          f32x2 v;
          v.x = __uint_as_float(uarr[j] << 16);
          v.y = __uint_as_float(uarr[j] & 0xffff0000u);
          acc2[j] += v * w;
        }
      }
    }
  }

  // combine halves and write (half 0 lanes)
  float accf[8];
#pragma unroll
  for (int j = 0; j < 4; ++j) {
    accf[2 * j] = acc2[j].x + __shfl_xor(acc2[j].x, 1);
    accf[2 * j + 1] = acc2[j].y + __shfl_xor(acc2[j].y, 1);
  }
  if (half == 0) {
    ushortx8 sv;
#pragma unroll
    for (int dd = 0; dd < 8; ++dd) sv[dd] = f2bu(accf[dd]);
    *(ushortx8*)(outp + ((size_t)b * HW + pix) * 32 + hh * 8) = sv;
  }
}

// ---------------------------------------------------------------------------
// srcframe[:,1] fp32 NCHW -> out1b NHWC-64 ch32..63 (bf16)
// ---------------------------------------------------------------------------
__global__ __launch_bounds__(256) void copy_src(const float* __restrict__ src,
                                                unsigned* __restrict__ out1b) {
  int pix = blockIdx.x * 256 + threadIdx.x;
  int b = blockIdx.y;
  const float* s = src + ((size_t)(b * 3 + 1) * 32) * HW + pix;
  unsigned u[16];
#pragma unroll
  for (int j = 0; j < 16; ++j)
    u[j] = pk2(s[(size_t)(2 * j) * HW], s[(size_t)(2 * j + 1) * HW]);
  unsigned* d = out1b + ((size_t)b * HW + pix) * 32 + 16;
#pragma unroll
  for (int j = 0; j < 4; ++j) {
    uint4 w;
    w.x = u[4 * j]; w.y = u[4 * j + 1]; w.z = u[4 * j + 2]; w.w = u[4 * j + 3];
    *(uint4*)&d[4 * j] = w;
  }
}

// ---------------------------------------------------------------------------
// final 1x1 conv + lrelu: out2 NHWC-32 f32 -> d_out fp32 NCHW
// ---------------------------------------------------------------------------
__global__ __launch_bounds__(256) void conv1x1_fu(
    const float* __restrict__ in, const float* __restrict__ wgt,
    const float* __restrict__ bias, float* __restrict__ out) {
  int pix = blockIdx.x * 256 + threadIdx.x;
  int b = blockIdx.y;
  float vin[32];
  {
    const f32x4* s = (const f32x4*)(in + ((size_t)b * HW + pix) * 32);
#pragma unroll
    for (int j = 0; j < 8; ++j) {
      f32x4 v = s[j];
#pragma unroll
      for (int e = 0; e < 4; ++e) vin[4 * j + e] = v[e];
    }
  }
#pragma unroll 1
  for (int oc = 0; oc < 32; ++oc) {
    float a = bias[oc];
#pragma unroll
    for (int ci = 0; ci < 32; ++ci) a = fmaf(wgt[oc * 32 + ci], vin[ci], a);
    a = a >= 0.f ? a : 0.1f * a;
    out[((size_t)b * 32 + oc) * HW + pix] = a;
  }
}

// ---------------------------------------------------------------------------
extern "C" void kernel_launch(void* const* d_in, const int* in_sizes, int n_in,
                              void* d_out, int out_size, void* d_ws, size_t ws_size,
                              hipStream_t stream) {
  (void)in_sizes; (void)n_in; (void)out_size;
  // Footprint: 25,614,592 floats = 102.46 MB (same as prior rounds, known OK).
  if (ws_size < 25614592ull * 4) return;

  const float* frame = (const float*)d_in[0];
  const float* srcframe = (const float*)d_in[1];
  const float* flowf = (const float*)d_in[2];
  const float* flowb = (const float*)d_in[3];

  float* ws = (float*)d_ws;
  us* wsu = (us*)d_ws;

  // bf16 weights, offsets in shorts (end 373,248 = 186,624 fl)
  static const int w2off[9] = {0,      110592, 193536, 202752, 285696,
                               327168, 336384, 345600, 364032};
  // Activation slots (float offsets):
  //  S1 @   186,624 (6,291,456): fnhwc -> offb -> ff1out
  //  S2 @ 6,478,080 (6,553,600): qk -> V -> awb(f32) -> out1b
  //  S3 @13,031,680 (6,291,456): Q -> attn + convout -> out2(f32)
  //  S4 @19,323,136 (6,291,456): Vp -> out1f(f32)
  us* fnhwc = (us*)(ws + 186624);
  unsigned* qk_u = (unsigned*)(ws + 6478080);
  us* qk = (us*)qk_u;
  us* Q = (us*)(ws + 13031680);
  us* V = (us*)(ws + 6478080);
  us* Vp = (us*)(ws + 19323136);
  us* offb = (us*)(ws + 186624);
  float* awb = (float*)(ws + 6478080);
  us* attn = (us*)(ws + 13031680);
  us* convout = (us*)(ws + 13031680 + 2097152);
  us* out1b = (us*)(ws + 6478080);
  unsigned* out1b_u = (unsigned*)out1b;
  float* out1f = (float*)(ws + 19323136);
  us* ff1out = (us*)(ws + 186624);
  float* out2 = (float*)(ws + 13031680);

  // 1) weight prep (LAY=1 m32-chunk layout for qk/v/off; burst for the rest)
  {
    PrepArgs pa;
    static const int srcidx[9] = {4, 6, 8, 10, 12, 14, 16, 18, 20};
    static const int OCs[9] = {96, 96, 32, 96, 48, 32, 32, 32, 32};
    static const int CINs[9] = {100, 96, 32, 96, 96, 32, 32, 64, 32};
    static const int KPADs[9] = {128, 96, 32, 96, 96, 32, 32, 64, 32};
    static const int LAYs[9] = {1, 1, 0, 1, 0, 0, 0, 0, 0};
    for (int i = 0; i < 9; ++i) {
      pa.src[i] = (const float*)d_in[srcidx[i]];
      pa.dst[i] = wsu + w2off[i];
      pa.OC[i] = OCs[i];
      pa.CIN[i] = CINs[i];
      pa.KPAD[i] = KPADs[i];
      pa.LAY[i] = LAYs[i];
    }
    prep_weights<<<dim3(432, 9), 256, 0, stream>>>(pa);
  }

  // 2) frame -> NHWC bf16
  frame_to_nhwc<<<dim3(256, 2), 256, 0, stream>>>(frame, (unsigned*)fnhwc);

  // 3) qk_in NHWC-100
  build_qkin<<<dim3(256, 2), 256, 0, stream>>>(fnhwc, flowf, flowb, qk_u);

  dim3 cg2(16, 32, 2);

  // 4) qureys = lrelu(conv_qk)  100->96  (m32: KPAD=128, OCT=3, KHC=4)
  conv3x3_m32<100, 100, 128, 3, 4, true><<<cg2, 256, 0, stream>>>(
      qk, wsu + w2off[0], (const float*)d_in[5], Q, 96, 0);

  // 5) value = conv_v(fnhwc) 96->96  (m32: KPAD=96, OCT=3, KHC=6)
  conv3x3_m32<96, 96, 96, 3, 6, false><<<cg2, 256, 0, stream>>>(
      fnhwc, wsu + w2off[1], (const float*)d_in[7], V, 96, 0);

  // 6) val = conv_vp per (b,l) 32->32 -> Vp [6][HW][32]
  conv3x3_mfma<32, 96, 32, 1, 2, 3, 32, 0, 0, false><<<dim3(16, 32, 6), 256, 0, stream>>>(
      V, wsu + w2off[2], (const float*)d_in[9], Vp, 32, 0, nullptr, nullptr, 0, 0);

  // 7) off = conv_off(Q) 96->96 (m32)  (S1; fnhwc dead)
  conv3x3_m32<96, 96, 96, 3, 6, false><<<cg2, 256, 0, stream>>>(
      Q, wsu + w2off[3], (const float*)d_in[11], offb, 96, 0);

  // 8) aw = conv_aw(Q) 96->48 f32 NHWC (S2; V dead)  G=3
  conv3x3_mfma<96, 96, 96, 1, 3, 1, 0, 0, 2, false><<<cg2, 256, 0, stream>>>(
      Q, wsu + w2off[4], (const float*)d_in[13], awb, 48, 0, nullptr, nullptr, 0, 0);

  // 9) deformable attention -> attn (S3; Q dead)  [(pixel,head,half)-parallel]
  deform_attn<<<dim3(2048, 2), 256, 0, stream>>>(Vp, offb, awb, attn);

  // 10) conv_out(attn) 32->32 (S3 tail)
  conv3x3_mfma<32, 32, 32, 1, 2, 1, 0, 0, 0, false><<<cg2, 256, 0, stream>>>(
      attn, wsu + w2off[5], (const float*)d_in[15], convout, 32, 0, nullptr, nullptr, 0, 0);

  // 11) out1 = conv_ffd(convout) + frame[:,1] -> out1b(NHWC-64 bf16) + out1f(f32)
  conv3x3_mfma<32, 32, 32, 1, 2, 1, 0, 2, 3, false><<<cg2, 256, 0, stream>>>(
      convout, wsu + w2off[6], (const float*)d_in[17], out1b, 64, 0, out1f, frame, 96, 32);

  // 12) srcframe[:,1] -> out1b ch32..63
  copy_src<<<dim3(256, 2), 256, 0, stream>>>(srcframe, out1b_u);

  // 13) ff1 = lrelu(conv dil=2 on out1b 64ch) -> ff1out (S1; offb dead)
  conv3x3_mfma<64, 64, 64, 2, 2, 1, 0, 0, 0, true><<<cg2, 256, 0, stream>>>(
      out1b, wsu + w2off[7], (const float*)d_in[19], ff1out, 32, 0, nullptr, nullptr, 0, 0);

  // 14) out2 = conv_ff2(ff1out) + out1f -> f32 NHWC-32 (S3; attn/convout dead)
  conv3x3_mfma<32, 32, 32, 1, 2, 1, 0, 1, 2, false><<<cg2, 256, 0, stream>>>(
      ff1out, wsu + w2off[8], (const float*)d_in[21], out2, 32, 0, nullptr, out1f, 32, 0);

  // 15) out = lrelu(conv_fu 1x1(out2)) -> fp32 NCHW d_out
  conv1x1_fu<<<dim3(256, 2), 256, 0, stream>>>(out2, (const float*)d_in[22],
                                               (const float*)d_in[23], (float*)d_out);
}

// Round 8
// 460.533 us; speedup vs baseline: 1.1102x; 1.0017x over previous
//
#include <hip/hip_runtime.h>
#include <hip/hip_bf16.h>

typedef __hip_bfloat16 bf16;
typedef unsigned short us;
typedef unsigned int u32;
typedef __attribute__((ext_vector_type(8))) short short8;
typedef __attribute__((ext_vector_type(8))) unsigned short ushortx8;
typedef __attribute__((ext_vector_type(2))) float f32x2;
typedef __attribute__((ext_vector_type(4))) float f32x4;
typedef __attribute__((ext_vector_type(16))) float f32x16;

#define HW 65536
#define IMW 256
#define IMH 256

static __device__ __forceinline__ float u2f(us u) {
  return __uint_as_float(((unsigned)u) << 16);
}
static __device__ __forceinline__ us f2bu(float x) {
  bf16 h = __float2bfloat16(x);
  return *reinterpret_cast<us*>(&h);
}
static __device__ __forceinline__ unsigned pk2(float a, float b) {
  return (unsigned)f2bu(a) | ((unsigned)f2bu(b) << 16);
}

// async global->LDS 16B: per-lane global src, wave-uniform LDS dest
static __device__ __forceinline__ void gload_lds16(const void* g, void* l) {
  __builtin_amdgcn_global_load_lds(
      (const __attribute__((address_space(1))) u32*)g,
      (__attribute__((address_space(3))) u32*)l, 16, 0, 0);
}

// ---------------------------------------------------------------------------
// Weight prep. Two layouts:
// LAY=0 (burst, for 16x16 template): [t][g][kc][q][m][8]; oc=g*16+m, k=kc*32+q*8+e
// LAY=1 (m32v2 stages): [sg][khi][j][lane][8] where sg=(kchunk*9+tap),
//        khi in [0,KCH/16), oc=j*32+(lane&31), k=kchunk*KCH+khi*16+(lane>>5)*8+e
// Both zero-pad K to KPAD.
// ---------------------------------------------------------------------------
struct PrepArgs {
  const float* src[9];
  us* dst[9];
  int OC[9], CIN[9], KPAD[9], LAY[9], KCH[9];
};

__global__ __launch_bounds__(256) void prep_weights(PrepArgs a) {
  int j = blockIdx.y;
  int n = blockIdx.x * 256 + threadIdx.x;
  int OC = a.OC[j], CIN = a.CIN[j], KPAD = a.KPAD[j];
  int tot = 9 * OC * KPAD;
  if (n >= tot) return;
  int oc, k;
  if (a.LAY[j] == 0) {
    int G = OC >> 4, NKC = KPAD >> 5;
    int e = n & 7;
    int m = (n >> 3) & 15;
    int q = (n >> 7) & 3;
    int rest = n >> 9;          // (t*G + g)*NKC + kc
    int kc = rest % NKC;
    int tg = rest / NKC;
    int g = tg % G;
    int t = tg / G;
    oc = g * 16 + m;
    k = kc * 32 + q * 8 + e;
    float v = (k < CIN) ? a.src[j][(size_t)(oc * CIN + k) * 9 + t] : 0.f;
    a.dst[j][n] = f2bu(v);
  } else {
    int OCT = OC >> 5;
    int KCH = a.KCH[j];
    int KHH = KCH >> 4;
    int e = n & 7;
    int l = (n >> 3) & 63;
    int rest = n >> 9;          // (sg*KHH + khi)*OCT + jt
    int jt = rest % OCT;
    int u = rest / OCT;
    int khi = u % KHH;
    int sg = u / KHH;
    int kc = sg / 9;
    oc = jt * 32 + (l & 31);
    k = kc * KCH + khi * 16 + (l >> 5) * 8 + e;
    int t = sg - kc * 9;
    float v = (k < CIN) ? a.src[j][(size_t)(oc * CIN + k) * 9 + t] : 0.f;
    a.dst[j][n] = f2bu(v);
  }
}

// ---------------------------------------------------------------------------
// frame fp32 NCHW [b][96][HW] -> NHWC bf16 [b][HW][96]
// ---------------------------------------------------------------------------
__global__ __launch_bounds__(256) void frame_to_nhwc(const float* __restrict__ frame,
                                                     unsigned* __restrict__ fn) {
  int pix = blockIdx.x * 256 + threadIdx.x;
  int b = blockIdx.y;
  const float* s = frame + (size_t)b * 96 * HW + pix;
  unsigned u[48];
#pragma unroll
  for (int j = 0; j < 48; ++j)
    u[j] = pk2(s[(size_t)(2 * j) * HW], s[(size_t)(2 * j + 1) * HW]);
  unsigned* d = fn + ((size_t)b * HW + pix) * 48;
#pragma unroll
  for (int j = 0; j < 12; ++j) {
    uint4 w;
    w.x = u[4 * j]; w.y = u[4 * j + 1]; w.z = u[4 * j + 2]; w.w = u[4 * j + 3];
    *(uint4*)&d[4 * j] = w;
  }
}

// ---------------------------------------------------------------------------
// qk_in build from NHWC frame: warp01 | frame[:,1] | warp21 | flows
// -> qk NHWC bf16 [b][HW][100]
// ---------------------------------------------------------------------------
static __device__ void warp_nhwc(const us* __restrict__ fn, size_t bbase, int coff,
                                 float x, float y, unsigned* uo) {
  float x0f = floorf(x), y0f = floorf(y);
  float lx = x - x0f, ly = y - y0f;
  int x0 = (int)x0f, y0 = (int)y0f;
  float wt[4] = {(1.f - lx) * (1.f - ly), lx * (1.f - ly), (1.f - lx) * ly, lx * ly};
  float acc[32] = {};
#pragma unroll
  for (int k = 0; k < 4; ++k) {
    int xi = x0 + (k & 1), yi = y0 + (k >> 1);
    if ((unsigned)xi < IMW && (unsigned)yi < IMH) {
      const ushortx8* s =
          (const ushortx8*)(fn + (bbase + (size_t)yi * IMW + xi) * 96 + coff);
      float w = wt[k];
#pragma unroll
      for (int cj = 0; cj < 4; ++cj) {
        ushortx8 vv = s[cj];
#pragma unroll
        for (int e = 0; e < 8; ++e)
          acc[cj * 8 + e] = fmaf(w, u2f(vv[e]), acc[cj * 8 + e]);
      }
    }
  }
#pragma unroll
  for (int j = 0; j < 16; ++j) uo[j] = pk2(acc[2 * j], acc[2 * j + 1]);
}

__global__ __launch_bounds__(256) void build_qkin(
    const us* __restrict__ fn, const float* __restrict__ flowf,
    const float* __restrict__ flowb, unsigned* __restrict__ qk) {
  int pix = blockIdx.x * 256 + threadIdx.x;
  int b = blockIdx.y;
  int px = pix & 255, py = pix >> 8;

  float fbx = flowb[((size_t)(b * 2 + 0) * 2 + 0) * HW + pix];
  float fby = flowb[((size_t)(b * 2 + 0) * 2 + 1) * HW + pix];
  float ffx = flowf[((size_t)(b * 2 + 1) * 2 + 0) * HW + pix];
  float ffy = flowf[((size_t)(b * 2 + 1) * 2 + 1) * HW + pix];

  unsigned u[50];
  {
    const unsigned* s = (const unsigned*)(fn + ((size_t)b * HW + pix) * 96);
#pragma unroll
    for (int j = 0; j < 16; ++j) u[16 + j] = s[16 + j];
  }
  u[48] = pk2(ffx, ffy);
  u[49] = pk2(fbx, fby);

  warp_nhwc(fn, (size_t)b * HW, 0, (float)px + fbx, (float)py + fby, &u[0]);
  warp_nhwc(fn, (size_t)b * HW, 64, (float)px + ffx, (float)py + ffy, &u[32]);

  unsigned* qb = qk + ((size_t)b * HW + pix) * 50;
#pragma unroll
  for (int j = 0; j < 25; ++j) {
    uint2 t;
    t.x = u[2 * j];
    t.y = u[2 * j + 1];
    *(uint2*)(qb + 2 * j) = t;
  }
}

// ---------------------------------------------------------------------------
// r8: m32v2 — 32x32x16-MFMA implicit-GEMM 3x3 conv, OC multiple of 32.
// Tile 32x8 px, 4 waves; wave wv owns rows {2wv,2wv+1} x cols 0..31 (64 px =
// 2 B-frags), all OCT oc-groups. Per khr: 2 B-reads + OCT A-reads -> 2*OCT
// MFMAs (0.83 KB LDS-read per MFMA vs 1.33 in r6-r7).
// Act staged in K-chunks of KCH=32 ch (CIPAD=40 -> 27.2 KB act LDS); weights
// stream via double-buffered gload_lds stages [sg][khi][j][lane][8].
// Total LDS ~39.5 KB -> 4 blocks/CU (vs 2), attacking the barrier-latency
// profile (r7: MfmaUtil 22 / VALU 15 / LDS 43% / HBM 10 - nothing saturated).
// B-frag lane map: n=lane&31 -> (subrow n>>4, col n&15); k=(lane>>5)*8+e.
// C/D (HW-verified): col=lane&31, row=(reg&3)+8*(reg>>2)+4*(lane>>5).
// ---------------------------------------------------------------------------
template <int CIN, int CST, int KPAD, int KCH, int OCT, bool LRELU>
__global__ __launch_bounds__(256) void conv3x3_m32(
    const us* __restrict__ in, const us* __restrict__ W2,
    const float* __restrict__ bias, us* __restrict__ out, int out_cst,
    int out_coff) {
  constexpr int COLS = 34, ROWS = 10, HALO = COLS * ROWS;
  constexpr int CIPAD = KCH + 8;        // 40 shorts = 80B rows (16B aligned)
  constexpr int CHc = KCH / 8;
  constexpr int KHH = KCH / 16;         // khr iterations per stage
  constexpr int NCH = KPAD / KCH;
  constexpr int NSTG = NCH * 9;
  constexpr int CHB = KHH * OCT;        // 1KB blocks per weight stage
  __shared__ alignas(16) short lds[HALO * CIPAD];
  __shared__ alignas(16) short wlds[2][CHB * 512];

  const int z = blockIdx.z;
  const int px0 = blockIdx.x * 32, py0 = blockIdx.y * 8;
  const int lane = threadIdx.x & 63;
  const int wv = threadIdx.x >> 6;
  const int n = lane & 31;
  const int sr = n >> 4;
  const int colp = n & 15;
  const int kq = lane >> 5;

  f32x16 acc[2][OCT];
#pragma unroll
  for (int f = 0; f < 2; ++f)
#pragma unroll
    for (int j = 0; j < OCT; ++j) acc[f][j] = 0.f;

  const int rb = 2 * wv + sr;           // local output row 0..7
  const int base0 = ((rb + 1) * COLS + colp + 1) * CIPAD + kq * 8;
  const int base1 = base0 + 16 * CIPAD;

  int buf = 0, sg = 0;
#pragma unroll 1
  for (int kc = 0; kc < NCH; ++kc) {
    // ---- stage act K-chunk into LDS [pos][ci_local], coalesced --------
    for (int c = threadIdx.x; c < HALO * CHc; c += 256) {
      int p = c / CHc, cb = c - p * CHc;
      int row = p / COLS, col = p - row * COLS;
      int gy = py0 + row - 1, gx = px0 + col - 1;
      bool ok = ((unsigned)gy < IMH) && ((unsigned)gx < IMW);
      int cil = cb * 8;
      int cig = kc * KCH + cil;
      const us* gp = in + ((size_t)z * HW + (size_t)gy * IMW + gx) * CST + cig;
      if (CIN == KPAD) {
        short8 v = (short8)0;
        if (ok) v = *(const short8*)gp;
        *(short8*)&lds[p * CIPAD + cil] = v;
      } else {
        uint2 h0; h0.x = 0; h0.y = 0;
        uint2 h1; h1.x = 0; h1.y = 0;
        if (ok && cig + 4 <= CIN) h0 = *(const uint2*)gp;
        if (ok && cig + 8 <= CIN) h1 = *(const uint2*)(gp + 4);
        *(uint2*)&lds[p * CIPAD + cil] = h0;
        *(uint2*)&lds[p * CIPAD + cil + 4] = h1;
      }
    }
    // ---- prestage weight stage 0 (async, drained by barrier) ----------
    if (kc == 0) {
#pragma unroll
      for (int r = 0; r < (CHB + 3) / 4; ++r) {
        int blk = r * 4 + wv;
        if (blk < CHB)
          gload_lds16(W2 + (size_t)(blk * 64 + lane) * 8, &wlds[0][blk * 512]);
      }
    }
    __syncthreads();

#pragma unroll 1
    for (int t = 0; t < 9; ++t, ++sg) {
      if (sg + 1 < NSTG) {
        const us* wn = W2 + (size_t)(sg + 1) * (CHB * 512);
#pragma unroll
        for (int r = 0; r < (CHB + 3) / 4; ++r) {
          int blk = r * 4 + wv;
          if (blk < CHB)
            gload_lds16(wn + (size_t)(blk * 64 + lane) * 8,
                        &wlds[buf ^ 1][blk * 512]);
        }
      }
      const int dy = t / 3 - 1, dx = t - (t / 3) * 3 - 1;
      const int toff = (dy * COLS + dx) * CIPAD;
#pragma unroll
      for (int khr = 0; khr < KHH; ++khr) {
        short8 bf0 = *(const short8*)&lds[base0 + toff + khr * 16];
        short8 bf1 = *(const short8*)&lds[base1 + toff + khr * 16];
#pragma unroll
        for (int j = 0; j < OCT; ++j) {
          short8 af =
              *(const short8*)&wlds[buf][(khr * OCT + j) * 512 + lane * 8];
          acc[0][j] = __builtin_amdgcn_mfma_f32_32x32x16_bf16(af, bf0,
                                                              acc[0][j], 0, 0, 0);
          acc[1][j] = __builtin_amdgcn_mfma_f32_32x32x16_bf16(af, bf1,
                                                              acc[1][j], 0, 0, 0);
        }
      }
      __syncthreads();
      buf ^= 1;
    }
  }

  // ---- epilogue -------------------------------------------------------
  {
    int row = py0 + rb;
#pragma unroll
    for (int f = 0; f < 2; ++f) {
      int pxc = px0 + 16 * f + colp;
      us* ob =
          out + ((size_t)z * HW + (size_t)row * IMW + pxc) * out_cst + out_coff;
#pragma unroll
      for (int j = 0; j < OCT; ++j) {
#pragma unroll
        for (int hi = 0; hi < 4; ++hi) {
          int oc0 = j * 32 + hi * 8 + kq * 4;
          f32x4 bb = *(const f32x4*)&bias[oc0];
          float v0 = acc[f][j][4 * hi + 0] + bb[0];
          float v1 = acc[f][j][4 * hi + 1] + bb[1];
          float v2 = acc[f][j][4 * hi + 2] + bb[2];
          float v3 = acc[f][j][4 * hi + 3] + bb[3];
          if (LRELU) {
            v0 = v0 >= 0.f ? v0 : 0.1f * v0;
            v1 = v1 >= 0.f ? v1 : 0.1f * v1;
            v2 = v2 >= 0.f ? v2 : 0.1f * v2;
            v3 = v3 >= 0.f ? v3 : 0.1f * v3;
          }
          uint2 w;
          w.x = pk2(v0, v1);
          w.y = pk2(v2, v3);
          *(uint2*)&ob[oc0] = w;
        }
      }
    }
  }
}

// ---------------------------------------------------------------------------
// 16x16x32 template (R4 structure). Used for the small convs + aw.
// ---------------------------------------------------------------------------
template <int CIN, int CST, int KPAD, int DIL, int G, int ZDIV, int CSUB,
          int RES, int OUTMODE, bool LRELU>
__global__ __launch_bounds__(256) void conv3x3_mfma(
    const us* __restrict__ in, const us* __restrict__ W2,
    const float* __restrict__ bias, void* __restrict__ out, int out_cst,
    int out_coff, float* __restrict__ outB, const float* __restrict__ res,
    int res_cst, int res_coff) {
  constexpr int OC = G * 16;
  constexpr int COLS = 16 + 2 * DIL;
  constexpr int ROWS = 8 + 2 * DIL;
  constexpr int HALO = ROWS * COLS;
  constexpr int CIPAD = KPAD + 8;
  constexpr int CH = KPAD / 8;
  constexpr int NKC = KPAD / 32;
  constexpr int GW0 = (G + 1) / 2;
  constexpr int NU = 9 * NKC;
  __shared__ alignas(16) short lds[HALO * CIPAD];

  const int z = blockIdx.z;
  const int bin = z / ZDIV;
  const int coff = (z % ZDIV) * CSUB;
  const int px0 = blockIdx.x * 16, py0 = blockIdx.y * 8;
  const int lane = threadIdx.x & 63;
  const int wv = threadIdx.x >> 6;
  const int m = lane & 15, q = lane >> 4;
  const int gh = wv & 1, rh = wv >> 1;
  const int goff = gh * GW0;

  f32x4 acc[GW0][4];
#pragma unroll
  for (int g = 0; g < GW0; ++g)
#pragma unroll
    for (int r = 0; r < 4; ++r) acc[g][r] = 0.f;

  for (int c = threadIdx.x; c < HALO * CH; c += 256) {
    int p = c / CH, cb = c - p * CH;
    int row = p / COLS, col = p - row * COLS;
    int gy = py0 + row - DIL, gx = px0 + col - DIL;
    bool ok = ((unsigned)gy < IMH) && ((unsigned)gx < IMW);
    int ci0 = cb * 8;
    const us* gp = in + ((size_t)bin * HW + (size_t)gy * IMW + gx) * CST + coff + ci0;
    if (CIN == KPAD) {
      short8 v = (short8)0;
      if (ok) v = *(const short8*)gp;
      *(short8*)&lds[p * CIPAD + ci0] = v;
    } else {
      uint2 h0; h0.x = 0; h0.y = 0;
      uint2 h1; h1.x = 0; h1.y = 0;
      if (ok && ci0 + 4 <= CIN) h0 = *(const uint2*)gp;
      if (ok && ci0 + 8 <= CIN) h1 = *(const uint2*)(gp + 4);
      *(uint2*)&lds[p * CIPAD + ci0] = h0;
      *(uint2*)&lds[p * CIPAD + ci0 + 4] = h1;
    }
  }
  __syncthreads();

  const us* wl = W2 + (size_t)lane * 8;
  short8 af[2][GW0];
#pragma unroll
  for (int g = 0; g < GW0; ++g)
    if (goff + g < G)
      af[0][g] = *(const short8*)(wl + (size_t)((goff + g) * NKC) * 512);

#pragma unroll
  for (int u = 0; u < NU; ++u) {
    const int t = u / NKC, kc = u - t * NKC;
    if (u + 1 < NU) {
      const int t1 = (u + 1) / NKC, kc1 = (u + 1) - t1 * NKC;
#pragma unroll
      for (int g = 0; g < GW0; ++g)
        if (goff + g < G)
          af[(u + 1) & 1][g] =
              *(const short8*)(wl + (size_t)((t1 * G + goff + g) * NKC + kc1) * 512);
    }
    const int dy = t / 3 - 1, dx = t - (t / 3) * 3 - 1;
    short8 bfr[4];
#pragma unroll
    for (int r = 0; r < 4; ++r) {
      int rr = rh * 4 + r + DIL + dy * DIL;
      int cc = m + DIL + dx * DIL;
      bfr[r] = *(const short8*)&lds[(rr * COLS + cc) * CIPAD + kc * 32 + q * 8];
    }
#pragma unroll
    for (int g = 0; g < GW0; ++g)
      if (goff + g < G)
#pragma unroll
        for (int r = 0; r < 4; ++r)
          acc[g][r] = __builtin_amdgcn_mfma_f32_16x16x32_bf16(af[u & 1][g], bfr[r],
                                                              acc[g][r], 0, 0, 0);
  }

#pragma unroll
  for (int g = 0; g < GW0; ++g) {
    if (goff + g < G) {
      int oc0 = (goff + g) * 16 + q * 4;
      f32x4 bb = *(const f32x4*)&bias[oc0];
#pragma unroll
      for (int r = 0; r < 4; ++r) {
        int py = py0 + rh * 4 + r;
        int px = px0 + m;
        size_t pix = (size_t)py * IMW + px;
        f32x4 v;
#pragma unroll
        for (int e = 0; e < 4; ++e) {
          float x = acc[g][r][e] + bb[e];
          if (LRELU) x = x >= 0.f ? x : 0.1f * x;
          v[e] = x;
        }
        if (RES == 1) {
          f32x4 rv = *(const f32x4*)&res[((size_t)z * HW + pix) * res_cst + oc0];
#pragma unroll
          for (int e = 0; e < 4; ++e) v[e] += rv[e];
        }
        if (RES == 2) {
#pragma unroll
          for (int e = 0; e < 4; ++e)
            v[e] += res[((size_t)z * res_cst + res_coff + oc0 + e) * HW + pix];
        }
        if (OUTMODE == 0 || OUTMODE == 3) {
          uint2 w;
          w.x = pk2(v[0], v[1]);
          w.y = pk2(v[2], v[3]);
          *(uint2*)&((us*)out)[((size_t)z * HW + pix) * out_cst + out_coff + oc0] = w;
        }
        if (OUTMODE == 2)
          *(f32x4*)&((float*)out)[((size_t)z * HW + pix) * out_cst + oc0] = v;
        if (OUTMODE == 3)
          *(f32x4*)&outB[((size_t)z * HW + pix) * 32 + oc0] = v;
      }
    }
  }
}

// ---------------------------------------------------------------------------
// Deformable attention v3 (r7, verified). (pixel, head, half)-parallel.
// ---------------------------------------------------------------------------
__global__ __launch_bounds__(256) void deform_attn(
    const us* __restrict__ valp, const us* __restrict__ off,
    const float* __restrict__ aw, us* __restrict__ outp) {
  int tid = threadIdx.x;
  int half = tid & 1;
  int hh = (tid >> 1) & 3;
  int pix = blockIdx.x * 32 + (tid >> 3);
  int b = blockIdx.y;
  int px = pix & (IMW - 1), py = pix >> 8;

  us os[12];
  {
    const uint2* ob = (const uint2*)(off + ((size_t)b * HW + pix) * 96 +
                                     hh * 24 + half * 12);
    uint2 a0 = ob[0], a1 = ob[1], a2 = ob[2];
    *(uint2*)&os[0] = a0;
    *(uint2*)&os[4] = a1;
    *(uint2*)&os[8] = a2;
  }
  float wv[6];
  {
    const f32x2* ab = (const f32x2*)(aw + ((size_t)b * HW + pix) * 48 +
                                     hh * 12 + half * 6);
    f32x2 a0 = ab[0], a1 = ab[1], a2 = ab[2];
    wv[0] = a0.x; wv[1] = a0.y; wv[2] = a1.x;
    wv[3] = a1.y; wv[4] = a2.x; wv[5] = a2.y;
  }

  float m6 = wv[0];
#pragma unroll
  for (int i = 1; i < 6; ++i) m6 = fmaxf(m6, wv[i]);
  float mx = fmaxf(m6, __shfl_xor(m6, 1));
  float s6 = 0.f;
#pragma unroll
  for (int i = 0; i < 6; ++i) {
    wv[i] = __expf(wv[i] - mx);
    s6 += wv[i];
  }
  float inv = 1.f / (s6 + __shfl_xor(s6, 1));

  f32x2 acc2[4];
#pragma unroll
  for (int j = 0; j < 4; ++j) acc2[j] = 0.f;

#pragma unroll
  for (int i = 0; i < 6; ++i) {
    int pp = half * 6 + i;
    int l = pp >> 2;
    const us* vbase = valp + ((size_t)(b * 3 + l) * HW) * 32 + hh * 8;
    float x = (float)px + u2f(os[2 * i]);
    float y = (float)py + u2f(os[2 * i + 1]);
    float x0f = floorf(x), y0f = floorf(y);
    float lx = x - x0f, ly = y - y0f;
    int x0 = (int)x0f, y0 = (int)y0f;
    bool vx0 = (unsigned)x0 < IMW, vx1 = (unsigned)(x0 + 1) < IMW;
    bool vy0 = (unsigned)y0 < IMH, vy1 = (unsigned)(y0 + 1) < IMH;
    float a = wv[i] * inv;
    float ax0 = (1.f - lx) * a, ax1 = lx * a;
    float w00 = ax0 * (1.f - ly), w01 = ax1 * (1.f - ly);
    float w10 = ax0 * ly, w11 = ax1 * ly;
    const us* p00 = vbase + (size_t)((long)(y0 * IMW + x0)) * 32;
#pragma unroll
    for (int c = 0; c < 4; ++c) {
      bool ok = (c & 1 ? vx1 : vx0) && (c & 2 ? vy1 : vy0);
      float w = (c == 0) ? w00 : (c == 1) ? w01 : (c == 2) ? w10 : w11;
      const us* p = p00 + (c & 1) * 32 + (c >> 1) * (IMW * 32);
      if (ok) {
        uint4 uu = *(const uint4*)p;
        unsigned uarr[4] = {uu.x, uu.y, uu.z, uu.w};
#pragma unroll
        for (int j = 0; j < 4; ++j) {
          f32x2 v;
          v.x = __uint_as_float(uarr[j] << 16);
          v.y = __uint_as_float(uarr[j] & 0xffff0000u);
          acc2[j] += v * w;
        }
      }
    }
  }

  float accf[8];
#pragma unroll
  for (int j = 0; j < 4; ++j) {
    accf[2 * j] = acc2[j].x + __shfl_xor(acc2[j].x, 1);
    accf[2 * j + 1] = acc2[j].y + __shfl_xor(acc2[j].y, 1);
  }
  if (half == 0) {
    ushortx8 sv;
#pragma unroll
    for (int dd = 0; dd < 8; ++dd) sv[dd] = f2bu(accf[dd]);
    *(ushortx8*)(outp + ((size_t)b * HW + pix) * 32 + hh * 8) = sv;
  }
}

// ---------------------------------------------------------------------------
// srcframe[:,1] fp32 NCHW -> out1b NHWC-64 ch32..63 (bf16)
// ---------------------------------------------------------------------------
__global__ __launch_bounds__(256) void copy_src(const float* __restrict__ src,
                                                unsigned* __restrict__ out1b) {
  int pix = blockIdx.x * 256 + threadIdx.x;
  int b = blockIdx.y;
  const float* s = src + ((size_t)(b * 3 + 1) * 32) * HW + pix;
  unsigned u[16];
#pragma unroll
  for (int j = 0; j < 16; ++j)
    u[j] = pk2(s[(size_t)(2 * j) * HW], s[(size_t)(2 * j + 1) * HW]);
  unsigned* d = out1b + ((size_t)b * HW + pix) * 32 + 16;
#pragma unroll
  for (int j = 0; j < 4; ++j) {
    uint4 w;
    w.x = u[4 * j]; w.y = u[4 * j + 1]; w.z = u[4 * j + 2]; w.w = u[4 * j + 3];
    *(uint4*)&d[4 * j] = w;
  }
}

// ---------------------------------------------------------------------------
// final 1x1 conv + lrelu: out2 NHWC-32 f32 -> d_out fp32 NCHW
// ---------------------------------------------------------------------------
__global__ __launch_bounds__(256) void conv1x1_fu(
    const float* __restrict__ in, const float* __restrict__ wgt,
    const float* __restrict__ bias, float* __restrict__ out) {
  int pix = blockIdx.x * 256 + threadIdx.x;
  int b = blockIdx.y;
  float vin[32];
  {
    const f32x4* s = (const f32x4*)(in + ((size_t)b * HW + pix) * 32);
#pragma unroll
    for (int j = 0; j < 8; ++j) {
      f32x4 v = s[j];
#pragma unroll
      for (int e = 0; e < 4; ++e) vin[4 * j + e] = v[e];
    }
  }
#pragma unroll 1
  for (int oc = 0; oc < 32; ++oc) {
    float a = bias[oc];
#pragma unroll
    for (int ci = 0; ci < 32; ++ci) a = fmaf(wgt[oc * 32 + ci], vin[ci], a);
    a = a >= 0.f ? a : 0.1f * a;
    out[((size_t)b * 32 + oc) * HW + pix] = a;
  }
}

// ---------------------------------------------------------------------------
extern "C" void kernel_launch(void* const* d_in, const int* in_sizes, int n_in,
                              void* d_out, int out_size, void* d_ws, size_t ws_size,
                              hipStream_t stream) {
  (void)in_sizes; (void)n_in; (void)out_size;
  // Footprint: 25,614,592 floats = 102.46 MB (same as prior rounds, known OK).
  if (ws_size < 25614592ull * 4) return;

  const float* frame = (const float*)d_in[0];
  const float* srcframe = (const float*)d_in[1];
  const float* flowf = (const float*)d_in[2];
  const float* flowb = (const float*)d_in[3];

  float* ws = (float*)d_ws;
  us* wsu = (us*)d_ws;

  // bf16 weights, offsets in shorts (end 373,248 = 186,624 fl)
  static const int w2off[9] = {0,      110592, 193536, 202752, 285696,
                               327168, 336384, 345600, 364032};
  // Activation slots (float offsets):
  //  S1 @   186,624 (6,291,456): fnhwc -> offb -> ff1out
  //  S2 @ 6,478,080 (6,553,600): qk -> V -> awb(f32) -> out1b
  //  S3 @13,031,680 (6,291,456): Q -> attn + convout -> out2(f32)
  //  S4 @19,323,136 (6,291,456): Vp -> out1f(f32)
  us* fnhwc = (us*)(ws + 186624);
  unsigned* qk_u = (unsigned*)(ws + 6478080);
  us* qk = (us*)qk_u;
  us* Q = (us*)(ws + 13031680);
  us* V = (us*)(ws + 6478080);
  us* Vp = (us*)(ws + 19323136);
  us* offb = (us*)(ws + 186624);
  float* awb = (float*)(ws + 6478080);
  us* attn = (us*)(ws + 13031680);
  us* convout = (us*)(ws + 13031680 + 2097152);
  us* out1b = (us*)(ws + 6478080);
  unsigned* out1b_u = (unsigned*)out1b;
  float* out1f = (float*)(ws + 19323136);
  us* ff1out = (us*)(ws + 186624);
  float* out2 = (float*)(ws + 13031680);

  // 1) weight prep (LAY=1 m32v2 stage layout for qk/v/off; burst for the rest)
  {
    PrepArgs pa;
    static const int srcidx[9] = {4, 6, 8, 10, 12, 14, 16, 18, 20};
    static const int OCs[9] = {96, 96, 32, 96, 48, 32, 32, 32, 32};
    static const int CINs[9] = {100, 96, 32, 96, 96, 32, 32, 64, 32};
    static const int KPADs[9] = {128, 96, 32, 96, 96, 32, 32, 64, 32};
    static const int LAYs[9] = {1, 1, 0, 1, 0, 0, 0, 0, 0};
    static const int KCHs[9] = {32, 32, 32, 32, 32, 32, 32, 32, 32};
    for (int i = 0; i < 9; ++i) {
      pa.src[i] = (const float*)d_in[srcidx[i]];
      pa.dst[i] = wsu + w2off[i];
      pa.OC[i] = OCs[i];
      pa.CIN[i] = CINs[i];
      pa.KPAD[i] = KPADs[i];
      pa.LAY[i] = LAYs[i];
      pa.KCH[i] = KCHs[i];
    }
    prep_weights<<<dim3(432, 9), 256, 0, stream>>>(pa);
  }

  // 2) frame -> NHWC bf16
  frame_to_nhwc<<<dim3(256, 2), 256, 0, stream>>>(frame, (unsigned*)fnhwc);

  // 3) qk_in NHWC-100
  build_qkin<<<dim3(256, 2), 256, 0, stream>>>(fnhwc, flowf, flowb, qk_u);

  dim3 cg2(16, 32, 2);
  dim3 cg32(8, 32, 2);

  // 4) qureys = lrelu(conv_qk)  100->96  (m32v2: KPAD=128, KCH=32, OCT=3)
  conv3x3_m32<100, 100, 128, 32, 3, true><<<cg32, 256, 0, stream>>>(
      qk, wsu + w2off[0], (const float*)d_in[5], Q, 96, 0);

  // 5) value = conv_v(fnhwc) 96->96  (m32v2)
  conv3x3_m32<96, 96, 96, 32, 3, false><<<cg32, 256, 0, stream>>>(
      fnhwc, wsu + w2off[1], (const float*)d_in[7], V, 96, 0);

  // 6) val = conv_vp per (b,l) 32->32 -> Vp [6][HW][32]
  conv3x3_mfma<32, 96, 32, 1, 2, 3, 32, 0, 0, false><<<dim3(16, 32, 6), 256, 0, stream>>>(
      V, wsu + w2off[2], (const float*)d_in[9], Vp, 32, 0, nullptr, nullptr, 0, 0);

  // 7) off = conv_off(Q) 96->96 (m32v2)  (S1; fnhwc dead)
  conv3x3_m32<96, 96, 96, 32, 3, false><<<cg32, 256, 0, stream>>>(
      Q, wsu + w2off[3], (const float*)d_in[11], offb, 96, 0);

  // 8) aw = conv_aw(Q) 96->48 f32 NHWC (S2; V dead)  G=3
  conv3x3_mfma<96, 96, 96, 1, 3, 1, 0, 0, 2, false><<<cg2, 256, 0, stream>>>(
      Q, wsu + w2off[4], (const float*)d_in[13], awb, 48, 0, nullptr, nullptr, 0, 0);

  // 9) deformable attention -> attn (S3; Q dead)  [(pixel,head,half)-parallel]
  deform_attn<<<dim3(2048, 2), 256, 0, stream>>>(Vp, offb, awb, attn);

  // 10) conv_out(attn) 32->32 (S3 tail)
  conv3x3_mfma<32, 32, 32, 1, 2, 1, 0, 0, 0, false><<<cg2, 256, 0, stream>>>(
      attn, wsu + w2off[5], (const float*)d_in[15], convout, 32, 0, nullptr, nullptr, 0, 0);

  // 11) out1 = conv_ffd(convout) + frame[:,1] -> out1b(NHWC-64 bf16) + out1f(f32)
  conv3x3_mfma<32, 32, 32, 1, 2, 1, 0, 2, 3, false><<<cg2, 256, 0, stream>>>(
      convout, wsu + w2off[6], (const float*)d_in[17], out1b, 64, 0, out1f, frame, 96, 32);

  // 12) srcframe[:,1] -> out1b ch32..63
  copy_src<<<dim3(256, 2), 256, 0, stream>>>(srcframe, out1b_u);

  // 13) ff1 = lrelu(conv dil=2 on out1b 64ch) -> ff1out (S1; offb dead)
  conv3x3_mfma<64, 64, 64, 2, 2, 1, 0, 0, 0, true><<<cg2, 256, 0, stream>>>(
      out1b, wsu + w2off[7], (const float*)d_in[19], ff1out, 32, 0, nullptr, nullptr, 0, 0);

  // 14) out2 = conv_ff2(ff1out) + out1f -> f32 NHWC-32 (S3; attn/convout dead)
  conv3x3_mfma<32, 32, 32, 1, 2, 1, 0, 1, 2, false><<<cg2, 256, 0, stream>>>(
      ff1out, wsu + w2off[8], (const float*)d_in[21], out2, 32, 0, nullptr, out1f, 32, 0);

  // 15) out = lrelu(conv_fu 1x1(out2)) -> fp32 NCHW d_out
  conv1x1_fu<<<dim3(256, 2), 256, 0, stream>>>(out2, (const float*)d_in[22],
                                               (const float*)d_in[23], (float*)d_out);
}